// Round 1
// baseline (342.406 us; speedup 1.0000x reference)
//
#include <hip/hip_runtime.h>

// ---------------------------------------------------------------------------
// ImplicitMLPAttention: B=4, N=1024, D=1024, H=16, DH=64, 3 attention layers.
// Pipeline: RMSNorm -> 7 projection GEMMs (bf16 MFMA) -> 3x fused causal
// flash-attention with RoPE (+SiLU between layers) -> final GEMM (f32 out).
// ---------------------------------------------------------------------------

typedef unsigned short u16;
typedef short s16x8 __attribute__((ext_vector_type(8)));
typedef u16 u16x4 __attribute__((ext_vector_type(4)));
typedef float f32x4 __attribute__((ext_vector_type(4)));

typedef __attribute__((address_space(1))) const unsigned int as1c_uint;
typedef __attribute__((address_space(3))) unsigned int as3_uint;

__device__ __forceinline__ float b2f(u16 h) {
  union { unsigned int u; float f; } v; v.u = ((unsigned int)h) << 16; return v.f;
}
__device__ __forceinline__ u16 f2b(float f) {
  union { float f; unsigned int u; } v; v.f = f;
  return (u16)((v.u + 0x7FFFu + ((v.u >> 16) & 1u)) >> 16);
}
// async global->LDS, 16B per lane. LDS dest must be wave-uniform base (+lane*16 in HW).
__device__ __forceinline__ void gload16(const u16* g, const u16* lds) {
  __builtin_amdgcn_global_load_lds((as1c_uint*)(size_t)g,
                                   (as3_uint*)(unsigned int)(size_t)lds, 16, 0, 0);
}

// ---------------------------------------------------------------------------
// RMSNorm: tokens f32 [4096,1024] -> x bf16, * gamma
// ---------------------------------------------------------------------------
__global__ __launch_bounds__(256)
void rmsnorm_kernel(const float* __restrict__ T, const float* __restrict__ gamma,
                    u16* __restrict__ X) {
  const int row = blockIdx.x, tid = threadIdx.x;
  const float4 v = ((const float4*)(T + (size_t)row * 1024))[tid];
  float ss = v.x * v.x + v.y * v.y + v.z * v.z + v.w * v.w;
#pragma unroll
  for (int msk = 1; msk <= 32; msk <<= 1) ss += __shfl_xor(ss, msk, 64);
  __shared__ float red[4];
  if ((tid & 63) == 0) red[tid >> 6] = ss;
  __syncthreads();
  const float tot = red[0] + red[1] + red[2] + red[3];
  const float r = rsqrtf(tot * (1.0f / 1024.0f) + 1.1920929e-07f);
  const float4 gm = ((const float4*)gamma)[tid];
  u16x4 o;
  o[0] = f2b(v.x * r * gm.x); o[1] = f2b(v.y * r * gm.y);
  o[2] = f2b(v.z * r * gm.z); o[3] = f2b(v.w * r * gm.w);
  *(u16x4*)(X + (size_t)row * 1024 + tid * 4) = o;
}

// ---------------------------------------------------------------------------
// RoPE tables: cos/sin [1024][32] f32 (theta=10000, interleaved pairs)
// ---------------------------------------------------------------------------
__global__ __launch_bounds__(256)
void rope_kernel(float* __restrict__ ct, float* __restrict__ st) {
  const int idx = blockIdx.x * 256 + threadIdx.x;  // 32768
  const int n = idx >> 5, j = idx & 31;
  const double freq = pow(10000.0, -(double)j / 32.0);
  const double a = (double)n * freq;
  ct[idx] = (float)cos(a);
  st[idx] = (float)sin(a);
}

// ---------------------------------------------------------------------------
// Weight transpose + bf16 cast: wt[z][n][k] = bf16(W_z[k][n]), z in 0..7
// z: 0=Wq, 1..3=Wk[i], 4..6=Wv[i], 7=Wo
// ---------------------------------------------------------------------------
__global__ __launch_bounds__(256)
void transw_kernel(const float* __restrict__ Wq, const float* __restrict__ Wk,
                   const float* __restrict__ Wv, const float* __restrict__ Wo,
                   u16* __restrict__ wt) {
  __shared__ float tile[32][33];
  const int z = blockIdx.z;
  const float* src = (z == 0) ? Wq
                   : (z <= 3) ? (Wk + (size_t)(z - 1) * 1048576)
                   : (z <= 6) ? (Wv + (size_t)(z - 4) * 1048576)
                              : Wo;
  u16* dst = wt + (size_t)z * 1048576;
  const int tx = threadIdx.x & 31, ty = threadIdx.x >> 5;
  const int bx = blockIdx.x * 32, by = blockIdx.y * 32;
#pragma unroll
  for (int i = 0; i < 4; ++i)
    tile[ty + i * 8][tx] = src[(size_t)(by + ty + i * 8) * 1024 + bx + tx];
  __syncthreads();
#pragma unroll
  for (int i = 0; i < 4; ++i)
    dst[(size_t)(bx + ty + i * 8) * 1024 + by + tx] = f2b(tile[tx][ty + i * 8]);
}

// ---------------------------------------------------------------------------
// GEMM: C[4096 x 1024] = A[4096,1024] * Bt[1024,1024]^T  (Bt row-major [n][k])
// 128x128 tile, BK=32, 256 thr = 4 waves (2x2), 4x4 16x16x32 MFMA frags/wave.
// KIND 0: projections, z=0..6 picks matrix; z>=4 (V) stored transposed
//         as [b][h][d][n] for attention's PV B-operand.
// KIND 1: final GEMM, f32 out.
// ---------------------------------------------------------------------------
template <int KIND>
__global__ __launch_bounds__(256)
void gemm_kernel(const u16* __restrict__ A, const u16* __restrict__ Bt,
                 void* __restrict__ Cout) {
  const int z = blockIdx.z;
  const int tid = threadIdx.x;
  const int w = tid >> 6, l = tid & 63;
  const int g = l >> 4, ll = l & 15;
  const int wr = w >> 1, wc = w & 1;
  const int m0 = blockIdx.y * 128, n0 = blockIdx.x * 128;

  const u16* Ab = A + (size_t)m0 * 1024;
  const u16* Bb = Bt + (size_t)z * 1048576 + (size_t)n0 * 1024;

  __shared__ u16 Ash[2][4096];
  __shared__ u16 Bsh[2][4096];

  const f32x4 zero = {0.f, 0.f, 0.f, 0.f};
  f32x4 acc[4][4];
#pragma unroll
  for (int i = 0; i < 4; ++i)
#pragma unroll
    for (int j = 0; j < 4; ++j) acc[i][j] = zero;

  const int sr = l >> 2;        // row within 16-row segment
  const int sc = (l & 3) * 8;   // k-offset 0,8,16,24

  auto stage = [&](int buf, int t) {
    const int k0 = t * 32;
#pragma unroll
    for (int j = 0; j < 2; ++j) {
      const int seg = j * 4 + w;           // 8 segments x 512 elems
      const int r = seg * 16 + sr;
      gload16(Ab + (size_t)r * 1024 + k0 + sc, &Ash[buf][seg * 512]);
      gload16(Bb + (size_t)r * 1024 + k0 + sc, &Bsh[buf][seg * 512]);
    }
  };

  stage(0, 0);
  __syncthreads();
  int buf = 0;
  for (int t = 0; t < 32; ++t) {
    if (t < 31) stage(buf ^ 1, t + 1);
    s16x8 af[4], bfr[4];
#pragma unroll
    for (int mf = 0; mf < 4; ++mf)
      af[mf] = *(const s16x8*)&Ash[buf][(wr * 64 + mf * 16 + ll) * 32 + g * 8];
#pragma unroll
    for (int nf = 0; nf < 4; ++nf)
      bfr[nf] = *(const s16x8*)&Bsh[buf][(wc * 64 + nf * 16 + ll) * 32 + g * 8];
#pragma unroll
    for (int mf = 0; mf < 4; ++mf)
#pragma unroll
      for (int nf = 0; nf < 4; ++nf)
        acc[mf][nf] = __builtin_amdgcn_mfma_f32_16x16x32_bf16(af[mf], bfr[nf],
                                                              acc[mf][nf], 0, 0, 0);
    __syncthreads();
    buf ^= 1;
  }

  if (KIND == 0) {
    u16* C = (u16*)Cout + (size_t)z * 4194304;
#pragma unroll
    for (int mf = 0; mf < 4; ++mf)
#pragma unroll
      for (int nf = 0; nf < 4; ++nf) {
        const int col = n0 + wc * 64 + nf * 16 + ll;
#pragma unroll
        for (int rg = 0; rg < 4; ++rg) {
          const int m = m0 + wr * 64 + mf * 16 + g * 4 + rg;
          const u16 val = f2b(acc[mf][nf][rg]);
          if (z < 4) {  // Q, K: token-major [b*N+n][h*64+d]
            C[(size_t)m * 1024 + col] = val;
          } else {      // V: transposed [((b*16+h)*64+d)][n]
            const int bb = m >> 10, n = m & 1023, hh = col >> 6, d = col & 63;
            C[((size_t)((bb * 16 + hh) * 64 + d)) * 1024 + n] = val;
          }
        }
      }
  } else {
    float* C = (float*)Cout;
#pragma unroll
    for (int mf = 0; mf < 4; ++mf)
#pragma unroll
      for (int nf = 0; nf < 4; ++nf) {
        const int col = n0 + wc * 64 + nf * 16 + ll;
#pragma unroll
        for (int rg = 0; rg < 4; ++rg) {
          const int m = m0 + wr * 64 + mf * 16 + g * 4 + rg;
          C[(size_t)m * 1024 + col] = acc[mf][nf][rg];
        }
      }
  }
}

// ---------------------------------------------------------------------------
// Fused causal flash attention with RoPE (+optional SiLU epilogue).
// Q,K token-major [b*N+n][h*64+d]; Vt transposed [(b*16+h)*64+d][n].
// Block: (qtile of 64 rows, bh). 4 waves x 16 q-rows each. KV tile = 64.
// ---------------------------------------------------------------------------
template <int SILU>
__global__ __launch_bounds__(256)
void attn_kernel(const u16* __restrict__ Q, const u16* __restrict__ K,
                 const u16* __restrict__ Vt, u16* __restrict__ O,
                 const float* __restrict__ ct, const float* __restrict__ st) {
  const int qt = blockIdx.x, bh = blockIdx.y;
  const int b = bh >> 4, h = bh & 15;
  const int tid = threadIdx.x, w = tid >> 6, l = tid & 63;
  const int g = l >> 4, ll = l & 15;

  const u16* Qb = Q + (size_t)(b * 1024) * 1024 + h * 64;
  const u16* Kb = K + (size_t)(b * 1024) * 1024 + h * 64;
  const u16* Vb = Vt + (size_t)((b * 16 + h) * 64) * 1024;
  u16* Ob = O + (size_t)(b * 1024) * 1024 + h * 64;

  __shared__ u16 Ksh[64 * 72];      // [kpos][d], roped, pad 72
  __shared__ u16 Vsh[64 * 72];      // [d][kpos], pad 72
  __shared__ u16 Psh[4][16 * 72];   // per-wave P round-trip, [q_local][kpos]

  // --- Q fragments: rope + 1/sqrt(64) scale, A-layout (row=ll, k=g*8+i) ---
  const int qrow = qt * 64 + w * 16 + ll;
  s16x8 qf[2];
#pragma unroll
  for (int kc = 0; kc < 2; ++kc) {
    const int d0 = kc * 32 + g * 8;
    const s16x8 qin = *(const s16x8*)(Qb + (size_t)qrow * 1024 + d0);
    s16x8 qo;
#pragma unroll
    for (int p = 0; p < 4; ++p) {
      const int j = (d0 >> 1) + p;
      const float c = ct[qrow * 32 + j], s = st[qrow * 32 + j];
      const float x0 = b2f((u16)qin[2 * p]), x1 = b2f((u16)qin[2 * p + 1]);
      qo[2 * p]     = (short)f2b((x0 * c - x1 * s) * 0.125f);
      qo[2 * p + 1] = (short)f2b((x1 * c + x0 * s) * 0.125f);
    }
    qf[kc] = qo;
  }

  float m[4], lsum[4];
  f32x4 o[4];
  const f32x4 zero = {0.f, 0.f, 0.f, 0.f};
#pragma unroll
  for (int rg = 0; rg < 4; ++rg) { m[rg] = -3.0e38f; lsum[rg] = 0.f; }
#pragma unroll
  for (int df = 0; df < 4; ++df) o[df] = zero;

  const int srow = tid >> 2;        // 0..63
  const int sc0 = (tid & 3) * 16;   // 0,16,32,48

  for (int t = 0; t <= qt; ++t) {
    // ---- stage K (rope fused) and Vt into LDS ----
    {
      const int n = t * 64 + srow;
      const u16* kp = Kb + (size_t)n * 1024 + sc0;
      const s16x8 k0v = *(const s16x8*)kp;
      const s16x8 k1v = *(const s16x8*)(kp + 8);
      s16x8 ko0, ko1;
#pragma unroll
      for (int p = 0; p < 4; ++p) {
        const int j = (sc0 >> 1) + p;
        const float c = ct[n * 32 + j], s = st[n * 32 + j];
        const float x0 = b2f((u16)k0v[2 * p]), x1 = b2f((u16)k0v[2 * p + 1]);
        ko0[2 * p]     = (short)f2b(x0 * c - x1 * s);
        ko0[2 * p + 1] = (short)f2b(x1 * c + x0 * s);
        const float c2 = ct[n * 32 + j + 4], s2 = st[n * 32 + j + 4];
        const float y0 = b2f((u16)k1v[2 * p]), y1 = b2f((u16)k1v[2 * p + 1]);
        ko1[2 * p]     = (short)f2b(y0 * c2 - y1 * s2);
        ko1[2 * p + 1] = (short)f2b(y1 * c2 + y0 * s2);
      }
      *(s16x8*)&Ksh[srow * 72 + sc0] = ko0;
      *(s16x8*)&Ksh[srow * 72 + sc0 + 8] = ko1;
      const u16* vp = Vb + (size_t)srow * 1024 + t * 64 + sc0;
      *(s16x8*)&Vsh[srow * 72 + sc0] = *(const s16x8*)vp;
      *(s16x8*)&Vsh[srow * 72 + sc0 + 8] = *(const s16x8*)(vp + 8);
    }
    __syncthreads();

    // ---- S = Q K^T (scaled; rope already applied) ----
    f32x4 s4[4];
#pragma unroll
    for (int nf = 0; nf < 4; ++nf) {
      const s16x8 kb0 = *(const s16x8*)&Ksh[(nf * 16 + ll) * 72 + g * 8];
      const s16x8 kb1 = *(const s16x8*)&Ksh[(nf * 16 + ll) * 72 + 32 + g * 8];
      f32x4 sv = zero;
      sv = __builtin_amdgcn_mfma_f32_16x16x32_bf16(qf[0], kb0, sv, 0, 0, 0);
      sv = __builtin_amdgcn_mfma_f32_16x16x32_bf16(qf[1], kb1, sv, 0, 0, 0);
      s4[nf] = sv;
    }

    if (t == qt) {  // causal mask inside diagonal tile
#pragma unroll
      for (int nf = 0; nf < 4; ++nf)
#pragma unroll
        for (int rg = 0; rg < 4; ++rg) {
          const int kg = t * 64 + nf * 16 + ll;
          const int qg = qt * 64 + w * 16 + g * 4 + rg;
          if (kg > qg) s4[nf][rg] = -3.0e38f;
        }
    }

    // ---- online softmax (rows live in 16-lane groups) ----
#pragma unroll
    for (int rg = 0; rg < 4; ++rg) {
      float rmax = fmaxf(fmaxf(s4[0][rg], s4[1][rg]), fmaxf(s4[2][rg], s4[3][rg]));
      rmax = fmaxf(rmax, __shfl_xor(rmax, 1, 64));
      rmax = fmaxf(rmax, __shfl_xor(rmax, 2, 64));
      rmax = fmaxf(rmax, __shfl_xor(rmax, 4, 64));
      rmax = fmaxf(rmax, __shfl_xor(rmax, 8, 64));
      const float mn = fmaxf(m[rg], rmax);
      const float scl = __expf(m[rg] - mn);
      m[rg] = mn;
      float ps = 0.f;
#pragma unroll
      for (int nf = 0; nf < 4; ++nf) {
        const float p = __expf(s4[nf][rg] - mn);
        s4[nf][rg] = p;
        ps += p;
      }
      lsum[rg] = lsum[rg] * scl + ps;   // lane-partial; reduced at the end
#pragma unroll
      for (int df = 0; df < 4; ++df) o[df][rg] *= scl;
    }

    // ---- P -> per-wave LDS (C-layout write, A-layout read) ----
#pragma unroll
    for (int nf = 0; nf < 4; ++nf)
#pragma unroll
      for (int rg = 0; rg < 4; ++rg)
        Psh[w][(g * 4 + rg) * 72 + nf * 16 + ll] = f2b(s4[nf][rg]);

    // ---- O += P V ----
#pragma unroll
    for (int kc = 0; kc < 2; ++kc) {
      const s16x8 pa = *(const s16x8*)&Psh[w][ll * 72 + kc * 32 + g * 8];
#pragma unroll
      for (int df = 0; df < 4; ++df) {
        const s16x8 vb = *(const s16x8*)&Vsh[(df * 16 + ll) * 72 + kc * 32 + g * 8];
        o[df] = __builtin_amdgcn_mfma_f32_16x16x32_bf16(pa, vb, o[df], 0, 0, 0);
      }
    }
    __syncthreads();
  }

  // ---- epilogue: normalize, optional SiLU, store token-major bf16 ----
#pragma unroll
  for (int rg = 0; rg < 4; ++rg) {
    float ls = lsum[rg];
    ls += __shfl_xor(ls, 1, 64);
    ls += __shfl_xor(ls, 2, 64);
    ls += __shfl_xor(ls, 4, 64);
    ls += __shfl_xor(ls, 8, 64);
    lsum[rg] = 1.f / ls;
  }
#pragma unroll
  for (int df = 0; df < 4; ++df)
#pragma unroll
    for (int rg = 0; rg < 4; ++rg) {
      float val = o[df][rg] * lsum[rg];
      if (SILU) val = val / (1.f + __expf(-val));
      Ob[(size_t)(qt * 64 + w * 16 + g * 4 + rg) * 1024 + df * 16 + ll] = f2b(val);
    }
}

// ---------------------------------------------------------------------------
extern "C" void kernel_launch(void* const* d_in, const int* in_sizes, int n_in,
                              void* d_out, int out_size, void* d_ws, size_t ws_size,
                              hipStream_t stream) {
  (void)in_sizes; (void)n_in; (void)out_size; (void)ws_size;
  const float* tokens = (const float*)d_in[0];
  const float* gamma  = (const float*)d_in[1];
  const float* Wq     = (const float*)d_in[2];
  const float* Wk     = (const float*)d_in[3];
  const float* Wv     = (const float*)d_in[4];
  const float* Wo     = (const float*)d_in[5];
  float* out = (float*)d_out;

  // workspace layout (bf16 elems unless noted); total ~96.3 MB
  u16* x    = (u16*)d_ws;                       // [4096][1024]
  u16* wt   = x + (size_t)4096 * 1024;          // 8 x [1024][1024] transposed bf16
  u16* qkv  = wt + (size_t)8 * 1048576;         // Q,K0..2,V0..2 each [4096][1024]
  u16* outA = qkv + (size_t)7 * 4194304;        // attn out ping
  u16* outB = outA + 4194304;                   // attn out pong
  float* ct = (float*)(outB + 4194304);         // cos [1024][32]
  float* st = ct + 32768;                       // sin [1024][32]

  rmsnorm_kernel<<<4096, 256, 0, stream>>>(tokens, gamma, x);
  rope_kernel<<<128, 256, 0, stream>>>(ct, st);
  transw_kernel<<<dim3(32, 32, 8), 256, 0, stream>>>(Wq, Wk, Wv, Wo, wt);
  gemm_kernel<0><<<dim3(8, 32, 7), 256, 0, stream>>>(x, wt, qkv);

  const size_t M4 = 4194304;
  attn_kernel<1><<<dim3(16, 64), 256, 0, stream>>>(qkv, qkv + 1 * M4, qkv + 4 * M4,
                                                   outA, ct, st);
  attn_kernel<1><<<dim3(16, 64), 256, 0, stream>>>(outA, qkv + 2 * M4, qkv + 5 * M4,
                                                   outB, ct, st);
  attn_kernel<0><<<dim3(16, 64), 256, 0, stream>>>(outB, qkv + 3 * M4, qkv + 6 * M4,
                                                   outA, ct, st);
  gemm_kernel<1><<<dim3(8, 32, 1), 256, 0, stream>>>(outA, wt + (size_t)7 * 1048576,
                                                     out);
}

// Round 2
// 309.377 us; speedup vs baseline: 1.1068x; 1.1068x over previous
//
#include <hip/hip_runtime.h>

// ---------------------------------------------------------------------------
// ImplicitMLPAttention: B=4, N=1024, D=1024, H=16, DH=64, 3 attention layers.
// RMSNorm -> 7 projection GEMMs (bf16 MFMA) -> pre-rope K -> 3x fused causal
// flash-attention (+SiLU between layers) -> final GEMM (f32 out).
// ---------------------------------------------------------------------------

typedef unsigned short u16;
typedef short s16x8 __attribute__((ext_vector_type(8)));
typedef u16 u16x4 __attribute__((ext_vector_type(4)));
typedef float f32x4 __attribute__((ext_vector_type(4)));

typedef __attribute__((address_space(1))) const unsigned int as1c_uint;
typedef __attribute__((address_space(3))) unsigned int as3_uint;

__device__ __forceinline__ float b2f(u16 h) {
  union { unsigned int u; float f; } v; v.u = ((unsigned int)h) << 16; return v.f;
}
__device__ __forceinline__ u16 f2b(float f) {
  union { float f; unsigned int u; } v; v.f = f;
  return (u16)((v.u + 0x7FFFu + ((v.u >> 16) & 1u)) >> 16);
}
// async global->LDS, 16B per lane. LDS dest must be wave-uniform base (+lane*16 in HW).
__device__ __forceinline__ void gload16(const u16* g, const u16* lds) {
  __builtin_amdgcn_global_load_lds((as1c_uint*)(size_t)g,
                                   (as3_uint*)(unsigned int)(size_t)lds, 16, 0, 0);
}

// ---------------------------------------------------------------------------
// RMSNorm: tokens f32 [4096,1024] -> x bf16, * gamma
// ---------------------------------------------------------------------------
__global__ __launch_bounds__(256)
void rmsnorm_kernel(const float* __restrict__ T, const float* __restrict__ gamma,
                    u16* __restrict__ X) {
  const int row = blockIdx.x, tid = threadIdx.x;
  const float4 v = ((const float4*)(T + (size_t)row * 1024))[tid];
  float ss = v.x * v.x + v.y * v.y + v.z * v.z + v.w * v.w;
#pragma unroll
  for (int msk = 1; msk <= 32; msk <<= 1) ss += __shfl_xor(ss, msk, 64);
  __shared__ float red[4];
  if ((tid & 63) == 0) red[tid >> 6] = ss;
  __syncthreads();
  const float tot = red[0] + red[1] + red[2] + red[3];
  const float r = rsqrtf(tot * (1.0f / 1024.0f) + 1.1920929e-07f);
  const float4 gm = ((const float4*)gamma)[tid];
  u16x4 o;
  o[0] = f2b(v.x * r * gm.x); o[1] = f2b(v.y * r * gm.y);
  o[2] = f2b(v.z * r * gm.z); o[3] = f2b(v.w * r * gm.w);
  *(u16x4*)(X + (size_t)row * 1024 + tid * 4) = o;
}

// ---------------------------------------------------------------------------
// RoPE tables: cos/sin [1024][32] f32 (theta=10000, interleaved pairs)
// ---------------------------------------------------------------------------
__global__ __launch_bounds__(256)
void rope_kernel(float* __restrict__ ct, float* __restrict__ st) {
  const int idx = blockIdx.x * 256 + threadIdx.x;  // 32768
  const int n = idx >> 5, j = idx & 31;
  const double freq = pow(10000.0, -(double)j / 32.0);
  const double a = (double)n * freq;
  ct[idx] = (float)cos(a);
  st[idx] = (float)sin(a);
}

// ---------------------------------------------------------------------------
// Pre-rope K in place: 3 buffers of [4096][1024] bf16, token-major.
// grid (4096 rows, 3 buffers), 256 thr, one u16x4 (2 pairs) per thread.
// ---------------------------------------------------------------------------
__global__ __launch_bounds__(256)
void ropek_kernel(u16* __restrict__ K, const float* __restrict__ ct,
                  const float* __restrict__ st) {
  u16* row = K + (size_t)blockIdx.y * 4194304 + (size_t)blockIdx.x * 1024;
  const int n = blockIdx.x & 1023;
  const int t = threadIdx.x;
  const int j = ((t * 4) & 63) >> 1;  // even pair index within head
  const float2 c2 = *(const float2*)(ct + n * 32 + j);
  const float2 s2 = *(const float2*)(st + n * 32 + j);
  u16x4 v = *(u16x4*)(row + t * 4);
  const float x0 = b2f(v[0]), x1 = b2f(v[1]);
  const float y0 = b2f(v[2]), y1 = b2f(v[3]);
  u16x4 o;
  o[0] = f2b(x0 * c2.x - x1 * s2.x);
  o[1] = f2b(x1 * c2.x + x0 * s2.x);
  o[2] = f2b(y0 * c2.y - y1 * s2.y);
  o[3] = f2b(y1 * c2.y + y0 * s2.y);
  *(u16x4*)(row + t * 4) = o;
}

// ---------------------------------------------------------------------------
// Weight transpose + bf16 cast: wt[z][n][k] = bf16(W_z[k][n]), z in 0..7
// ---------------------------------------------------------------------------
__global__ __launch_bounds__(256)
void transw_kernel(const float* __restrict__ Wq, const float* __restrict__ Wk,
                   const float* __restrict__ Wv, const float* __restrict__ Wo,
                   u16* __restrict__ wt) {
  __shared__ float tile[32][33];
  const int z = blockIdx.z;
  const float* src = (z == 0) ? Wq
                   : (z <= 3) ? (Wk + (size_t)(z - 1) * 1048576)
                   : (z <= 6) ? (Wv + (size_t)(z - 4) * 1048576)
                              : Wo;
  u16* dst = wt + (size_t)z * 1048576;
  const int tx = threadIdx.x & 31, ty = threadIdx.x >> 5;
  const int bx = blockIdx.x * 32, by = blockIdx.y * 32;
#pragma unroll
  for (int i = 0; i < 4; ++i)
    tile[ty + i * 8][tx] = src[(size_t)(by + ty + i * 8) * 1024 + bx + tx];
  __syncthreads();
#pragma unroll
  for (int i = 0; i < 4; ++i)
    dst[(size_t)(bx + ty + i * 8) * 1024 + by + tx] = f2b(tile[tx][ty + i * 8]);
}

// ---------------------------------------------------------------------------
// GEMM: C[4096 x 1024] = A[4096,1024] * Bt[1024,1024]^T  (Bt row-major [n][k])
// 128x128 tile, BK=32, 256 thr = 4 waves (2x2), 4x4 16x16x32 MFMA frags/wave.
// KIND 0: projections z=0..6; z>=4 (V) stored transposed [b][h][d][n].
// KIND 1: final GEMM, f32 out.
// ---------------------------------------------------------------------------
template <int KIND>
__global__ __launch_bounds__(256)
void gemm_kernel(const u16* __restrict__ A, const u16* __restrict__ Bt,
                 void* __restrict__ Cout) {
  const int z = blockIdx.z;
  const int tid = threadIdx.x;
  const int w = tid >> 6, l = tid & 63;
  const int g = l >> 4, ll = l & 15;
  const int wr = w >> 1, wc = w & 1;
  const int m0 = blockIdx.y * 128, n0 = blockIdx.x * 128;

  const u16* Ab = A + (size_t)m0 * 1024;
  const u16* Bb = Bt + (size_t)z * 1048576 + (size_t)n0 * 1024;

  __shared__ u16 Ash[2][4096];
  __shared__ u16 Bsh[2][4096];

  const f32x4 zero = {0.f, 0.f, 0.f, 0.f};
  f32x4 acc[4][4];
#pragma unroll
  for (int i = 0; i < 4; ++i)
#pragma unroll
    for (int j = 0; j < 4; ++j) acc[i][j] = zero;

  const int sr = l >> 2;        // row within 16-row segment
  const int sc = (l & 3) * 8;   // k-offset 0,8,16,24

  auto stage = [&](int buf, int t) {
    const int k0 = t * 32;
#pragma unroll
    for (int j = 0; j < 2; ++j) {
      const int seg = j * 4 + w;           // 8 segments x 512 elems
      const int r = seg * 16 + sr;
      gload16(Ab + (size_t)r * 1024 + k0 + sc, &Ash[buf][seg * 512]);
      gload16(Bb + (size_t)r * 1024 + k0 + sc, &Bsh[buf][seg * 512]);
    }
  };

  stage(0, 0);
  __syncthreads();
  int buf = 0;
  for (int t = 0; t < 32; ++t) {
    if (t < 31) stage(buf ^ 1, t + 1);
    s16x8 af[4], bfr[4];
#pragma unroll
    for (int mf = 0; mf < 4; ++mf)
      af[mf] = *(const s16x8*)&Ash[buf][(wr * 64 + mf * 16 + ll) * 32 + g * 8];
#pragma unroll
    for (int nf = 0; nf < 4; ++nf)
      bfr[nf] = *(const s16x8*)&Bsh[buf][(wc * 64 + nf * 16 + ll) * 32 + g * 8];
#pragma unroll
    for (int mf = 0; mf < 4; ++mf)
#pragma unroll
      for (int nf = 0; nf < 4; ++nf)
        acc[mf][nf] = __builtin_amdgcn_mfma_f32_16x16x32_bf16(af[mf], bfr[nf],
                                                              acc[mf][nf], 0, 0, 0);
    __syncthreads();
    buf ^= 1;
  }

  if (KIND == 0) {
    u16* C = (u16*)Cout + (size_t)z * 4194304;
#pragma unroll
    for (int mf = 0; mf < 4; ++mf)
#pragma unroll
      for (int nf = 0; nf < 4; ++nf) {
        const int col = n0 + wc * 64 + nf * 16 + ll;
#pragma unroll
        for (int rg = 0; rg < 4; ++rg) {
          const int m = m0 + wr * 64 + mf * 16 + g * 4 + rg;
          const u16 val = f2b(acc[mf][nf][rg]);
          if (z < 4) {  // Q, K: token-major [b*N+n][h*64+d]
            C[(size_t)m * 1024 + col] = val;
          } else {      // V: transposed [((b*16+h)*64+d)][n]
            const int bb = m >> 10, n = m & 1023, hh = col >> 6, d = col & 63;
            C[((size_t)((bb * 16 + hh) * 64 + d)) * 1024 + n] = val;
          }
        }
      }
  } else {
    float* C = (float*)Cout;
#pragma unroll
    for (int mf = 0; mf < 4; ++mf)
#pragma unroll
      for (int nf = 0; nf < 4; ++nf) {
        const int col = n0 + wc * 64 + nf * 16 + ll;
#pragma unroll
        for (int rg = 0; rg < 4; ++rg) {
          const int m = m0 + wr * 64 + mf * 16 + g * 4 + rg;
          C[(size_t)m * 1024 + col] = acc[mf][nf][rg];
        }
      }
  }
}

// ---------------------------------------------------------------------------
// Fused causal flash attention (+optional SiLU epilogue).
// Q token-major (roped here); K token-major PRE-ROPED; Vt [(b*16+h)*64+d][n].
// Block: (qtile of 64 rows, bh) via XCD-swizzled role. 4 waves x 16 q-rows.
// K double-buffered in LDS (1 barrier/tile); V read direct from global (L2).
// ---------------------------------------------------------------------------
template <int SILU>
__global__ __launch_bounds__(256)
void attn_kernel(const u16* __restrict__ Q, const u16* __restrict__ K,
                 const u16* __restrict__ Vt, u16* __restrict__ O,
                 const float* __restrict__ ct, const float* __restrict__ st) {
  // XCD swizzle: 16 q-blocks sharing one bh land on the same XCD (1024%8==0).
  const int lin = blockIdx.x + (blockIdx.y << 4);
  const int role = (lin & 7) * 128 + (lin >> 3);
  const int qt = role & 15, bh = role >> 4;
  const int b = bh >> 4, h = bh & 15;
  const int tid = threadIdx.x, w = tid >> 6, l = tid & 63;
  const int g = l >> 4, ll = l & 15;

  const u16* Qb = Q + (size_t)(b * 1024) * 1024 + h * 64;
  const u16* Kb = K + (size_t)(b * 1024) * 1024 + h * 64;
  const u16* Vb = Vt + (size_t)((b * 16 + h) * 64) * 1024;
  u16* Ob = O + (size_t)(b * 1024) * 1024 + h * 64;

  __shared__ u16 Ksh[2][64 * 72];   // [kpos][d] pre-roped, pad 72, dbuf
  __shared__ u16 Psh[4][16 * 72];   // per-wave P round-trip, [q_local][kpos]

  // --- Q fragments: rope + 1/sqrt(64) scale, A-layout (row=ll, k=g*8+i) ---
  const int qrow = qt * 64 + w * 16 + ll;
  s16x8 qf[2];
#pragma unroll
  for (int kc = 0; kc < 2; ++kc) {
    const int d0 = kc * 32 + g * 8;
    const int j0 = d0 >> 1;
    const float4 c4 = *(const float4*)(ct + qrow * 32 + j0);
    const float4 s4v = *(const float4*)(st + qrow * 32 + j0);
    const s16x8 qin = *(const s16x8*)(Qb + (size_t)qrow * 1024 + d0);
    s16x8 qo;
#pragma unroll
    for (int p = 0; p < 4; ++p) {
      const float c = ((const float*)&c4)[p], s = ((const float*)&s4v)[p];
      const float x0 = b2f((u16)qin[2 * p]), x1 = b2f((u16)qin[2 * p + 1]);
      qo[2 * p]     = (short)f2b((x0 * c - x1 * s) * 0.125f);
      qo[2 * p + 1] = (short)f2b((x1 * c + x0 * s) * 0.125f);
    }
    qf[kc] = qo;
  }

  float m[4], lsum[4];
  f32x4 o[4];
  const f32x4 zero = {0.f, 0.f, 0.f, 0.f};
#pragma unroll
  for (int rg = 0; rg < 4; ++rg) { m[rg] = -3.0e38f; lsum[rg] = 0.f; }
#pragma unroll
  for (int df = 0; df < 4; ++df) o[df] = zero;

  const int srow = tid >> 2;        // 0..63
  const int sc0 = (tid & 3) * 16;   // 0,16,32,48

  auto stageK = [&](int buf, int t) {
    const u16* kp = Kb + (size_t)(t * 64 + srow) * 1024 + sc0;
    *(s16x8*)&Ksh[buf][srow * 72 + sc0] = *(const s16x8*)kp;
    *(s16x8*)&Ksh[buf][srow * 72 + sc0 + 8] = *(const s16x8*)(kp + 8);
  };

  stageK(0, 0);
  __syncthreads();
  int buf = 0;

  for (int t = 0; t <= qt; ++t) {
    if (t < qt) stageK(buf ^ 1, t + 1);   // prefetch next K tile

    // ---- V fragments direct from global (L2-resident) ----
    s16x8 vb[2][4];
#pragma unroll
    for (int kc = 0; kc < 2; ++kc)
#pragma unroll
      for (int df = 0; df < 4; ++df)
        vb[kc][df] = *(const s16x8*)(Vb + (size_t)(df * 16 + ll) * 1024 +
                                     t * 64 + kc * 32 + g * 8);

    // ---- S = Q K^T ----
    f32x4 s4[4];
    __builtin_amdgcn_s_setprio(1);
#pragma unroll
    for (int nf = 0; nf < 4; ++nf) {
      const s16x8 kb0 = *(const s16x8*)&Ksh[buf][(nf * 16 + ll) * 72 + g * 8];
      const s16x8 kb1 = *(const s16x8*)&Ksh[buf][(nf * 16 + ll) * 72 + 32 + g * 8];
      f32x4 sv = zero;
      sv = __builtin_amdgcn_mfma_f32_16x16x32_bf16(qf[0], kb0, sv, 0, 0, 0);
      sv = __builtin_amdgcn_mfma_f32_16x16x32_bf16(qf[1], kb1, sv, 0, 0, 0);
      s4[nf] = sv;
    }
    __builtin_amdgcn_s_setprio(0);

    if (t == qt) {  // causal mask inside diagonal tile
#pragma unroll
      for (int nf = 0; nf < 4; ++nf)
#pragma unroll
        for (int rg = 0; rg < 4; ++rg) {
          const int kg = t * 64 + nf * 16 + ll;
          const int qg = qt * 64 + w * 16 + g * 4 + rg;
          if (kg > qg) s4[nf][rg] = -3.0e38f;
        }
    }

    // ---- online softmax (rows live in 16-lane groups) ----
#pragma unroll
    for (int rg = 0; rg < 4; ++rg) {
      float rmax = fmaxf(fmaxf(s4[0][rg], s4[1][rg]), fmaxf(s4[2][rg], s4[3][rg]));
      rmax = fmaxf(rmax, __shfl_xor(rmax, 1, 64));
      rmax = fmaxf(rmax, __shfl_xor(rmax, 2, 64));
      rmax = fmaxf(rmax, __shfl_xor(rmax, 4, 64));
      rmax = fmaxf(rmax, __shfl_xor(rmax, 8, 64));
      const float mn = fmaxf(m[rg], rmax);
      const float scl = __expf(m[rg] - mn);
      m[rg] = mn;
      float ps = 0.f;
#pragma unroll
      for (int nf = 0; nf < 4; ++nf) {
        const float p = __expf(s4[nf][rg] - mn);
        s4[nf][rg] = p;
        ps += p;
      }
      lsum[rg] = lsum[rg] * scl + ps;   // lane-partial; reduced at the end
#pragma unroll
      for (int df = 0; df < 4; ++df) o[df][rg] *= scl;
    }

    // ---- P -> per-wave LDS (C-layout write, A-layout read) ----
#pragma unroll
    for (int nf = 0; nf < 4; ++nf)
#pragma unroll
      for (int rg = 0; rg < 4; ++rg)
        Psh[w][(g * 4 + rg) * 72 + nf * 16 + ll] = f2b(s4[nf][rg]);

    // ---- O += P V ----
    __builtin_amdgcn_s_setprio(1);
#pragma unroll
    for (int kc = 0; kc < 2; ++kc) {
      const s16x8 pa = *(const s16x8*)&Psh[w][ll * 72 + kc * 32 + g * 8];
#pragma unroll
      for (int df = 0; df < 4; ++df)
        o[df] = __builtin_amdgcn_mfma_f32_16x16x32_bf16(pa, vb[kc][df], o[df], 0, 0, 0);
    }
    __builtin_amdgcn_s_setprio(0);

    __syncthreads();
    buf ^= 1;
  }

  // ---- epilogue: normalize, optional SiLU, store token-major bf16 ----
#pragma unroll
  for (int rg = 0; rg < 4; ++rg) {
    float ls = lsum[rg];
    ls += __shfl_xor(ls, 1, 64);
    ls += __shfl_xor(ls, 2, 64);
    ls += __shfl_xor(ls, 4, 64);
    ls += __shfl_xor(ls, 8, 64);
    lsum[rg] = 1.f / ls;
  }
#pragma unroll
  for (int df = 0; df < 4; ++df)
#pragma unroll
    for (int rg = 0; rg < 4; ++rg) {
      float val = o[df][rg] * lsum[rg];
      if (SILU) val = val / (1.f + __expf(-val));
      Ob[(size_t)(qt * 64 + w * 16 + g * 4 + rg) * 1024 + df * 16 + ll] = f2b(val);
    }
}

// ---------------------------------------------------------------------------
extern "C" void kernel_launch(void* const* d_in, const int* in_sizes, int n_in,
                              void* d_out, int out_size, void* d_ws, size_t ws_size,
                              hipStream_t stream) {
  (void)in_sizes; (void)n_in; (void)out_size; (void)ws_size;
  const float* tokens = (const float*)d_in[0];
  const float* gamma  = (const float*)d_in[1];
  const float* Wq     = (const float*)d_in[2];
  const float* Wk     = (const float*)d_in[3];
  const float* Wv     = (const float*)d_in[4];
  const float* Wo     = (const float*)d_in[5];
  float* out = (float*)d_out;

  // workspace layout (bf16 elems unless noted); total ~96.3 MB
  u16* x    = (u16*)d_ws;                       // [4096][1024]
  u16* wt   = x + (size_t)4096 * 1024;          // 8 x [1024][1024] transposed bf16
  u16* qkv  = wt + (size_t)8 * 1048576;         // Q,K0..2,V0..2 each [4096][1024]
  u16* outA = qkv + (size_t)7 * 4194304;        // attn out ping
  u16* outB = outA + 4194304;                   // attn out pong
  float* ct = (float*)(outB + 4194304);         // cos [1024][32]
  float* st = ct + 32768;                       // sin [1024][32]

  rmsnorm_kernel<<<4096, 256, 0, stream>>>(tokens, gamma, x);
  rope_kernel<<<128, 256, 0, stream>>>(ct, st);
  transw_kernel<<<dim3(32, 32, 8), 256, 0, stream>>>(Wq, Wk, Wv, Wo, wt);
  gemm_kernel<0><<<dim3(8, 32, 7), 256, 0, stream>>>(x, wt, qkv);

  const size_t M4 = 4194304;
  ropek_kernel<<<dim3(4096, 3), 256, 0, stream>>>(qkv + M4, ct, st);

  attn_kernel<1><<<dim3(16, 64), 256, 0, stream>>>(qkv, qkv + 1 * M4, qkv + 4 * M4,
                                                   outA, ct, st);
  attn_kernel<1><<<dim3(16, 64), 256, 0, stream>>>(outA, qkv + 2 * M4, qkv + 5 * M4,
                                                   outB, ct, st);
  attn_kernel<0><<<dim3(16, 64), 256, 0, stream>>>(outB, qkv + 3 * M4, qkv + 6 * M4,
                                                   outA, ct, st);
  gemm_kernel<1><<<dim3(8, 32, 1), 256, 0, stream>>>(outA, wt + (size_t)7 * 1048576,
                                                     out);
}

// Round 3
// 262.672 us; speedup vs baseline: 1.3036x; 1.1778x over previous
//
#include <hip/hip_runtime.h>

// ---------------------------------------------------------------------------
// ImplicitMLPAttention: B=4, N=1024, D=1024, H=16, DH=64, 3 attention layers.
// RMSNorm -> 7 projection GEMMs (bf16 MFMA) -> pre-rope K -> 3x fused causal
// flash-attention (paired q-tiles, +SiLU between layers) -> final GEMM
// (split-K2, f32) -> reduce.
// ---------------------------------------------------------------------------

typedef unsigned short u16;
typedef short s16x8 __attribute__((ext_vector_type(8)));
typedef u16 u16x4 __attribute__((ext_vector_type(4)));
typedef float f32x4 __attribute__((ext_vector_type(4)));

typedef __attribute__((address_space(1))) const unsigned int as1c_uint;
typedef __attribute__((address_space(3))) unsigned int as3_uint;

__device__ __forceinline__ float b2f(u16 h) {
  union { unsigned int u; float f; } v; v.u = ((unsigned int)h) << 16; return v.f;
}
__device__ __forceinline__ u16 f2b(float f) {
  union { float f; unsigned int u; } v; v.f = f;
  return (u16)((v.u + 0x7FFFu + ((v.u >> 16) & 1u)) >> 16);
}
// async global->LDS, 16B per lane. LDS dest must be wave-uniform base (+lane*16 in HW).
__device__ __forceinline__ void gload16(const u16* g, const u16* lds) {
  __builtin_amdgcn_global_load_lds((as1c_uint*)(size_t)g,
                                   (as3_uint*)(unsigned int)(size_t)lds, 16, 0, 0);
}

// ---------------------------------------------------------------------------
// RMSNorm: tokens f32 [4096,1024] -> x bf16, * gamma
// ---------------------------------------------------------------------------
__global__ __launch_bounds__(256)
void rmsnorm_kernel(const float* __restrict__ T, const float* __restrict__ gamma,
                    u16* __restrict__ X) {
  const int row = blockIdx.x, tid = threadIdx.x;
  const float4 v = ((const float4*)(T + (size_t)row * 1024))[tid];
  float ss = v.x * v.x + v.y * v.y + v.z * v.z + v.w * v.w;
#pragma unroll
  for (int msk = 1; msk <= 32; msk <<= 1) ss += __shfl_xor(ss, msk, 64);
  __shared__ float red[4];
  if ((tid & 63) == 0) red[tid >> 6] = ss;
  __syncthreads();
  const float tot = red[0] + red[1] + red[2] + red[3];
  const float r = rsqrtf(tot * (1.0f / 1024.0f) + 1.1920929e-07f);
  const float4 gm = ((const float4*)gamma)[tid];
  u16x4 o;
  o[0] = f2b(v.x * r * gm.x); o[1] = f2b(v.y * r * gm.y);
  o[2] = f2b(v.z * r * gm.z); o[3] = f2b(v.w * r * gm.w);
  *(u16x4*)(X + (size_t)row * 1024 + tid * 4) = o;
}

// ---------------------------------------------------------------------------
// RoPE tables: cos/sin [1024][32] f32 (theta=10000, interleaved pairs)
// ---------------------------------------------------------------------------
__global__ __launch_bounds__(256)
void rope_kernel(float* __restrict__ ct, float* __restrict__ st) {
  const int idx = blockIdx.x * 256 + threadIdx.x;  // 32768
  const int n = idx >> 5, j = idx & 31;
  const double freq = pow(10000.0, -(double)j / 32.0);
  const double a = (double)n * freq;
  ct[idx] = (float)cos(a);
  st[idx] = (float)sin(a);
}

// ---------------------------------------------------------------------------
// Pre-rope K in place: 3 buffers of [4096][1024] bf16, token-major.
// ---------------------------------------------------------------------------
__global__ __launch_bounds__(256)
void ropek_kernel(u16* __restrict__ K, const float* __restrict__ ct,
                  const float* __restrict__ st) {
  u16* row = K + (size_t)blockIdx.y * 4194304 + (size_t)blockIdx.x * 1024;
  const int n = blockIdx.x & 1023;
  const int t = threadIdx.x;
  const int j = ((t * 4) & 63) >> 1;  // even pair index within head
  const float2 c2 = *(const float2*)(ct + n * 32 + j);
  const float2 s2 = *(const float2*)(st + n * 32 + j);
  u16x4 v = *(u16x4*)(row + t * 4);
  const float x0 = b2f(v[0]), x1 = b2f(v[1]);
  const float y0 = b2f(v[2]), y1 = b2f(v[3]);
  u16x4 o;
  o[0] = f2b(x0 * c2.x - x1 * s2.x);
  o[1] = f2b(x1 * c2.x + x0 * s2.x);
  o[2] = f2b(y0 * c2.y - y1 * s2.y);
  o[3] = f2b(y1 * c2.y + y0 * s2.y);
  *(u16x4*)(row + t * 4) = o;
}

// ---------------------------------------------------------------------------
// Weight transpose + bf16 cast: wt[z][n][k] = bf16(W_z[k][n]), z in 0..7
// ---------------------------------------------------------------------------
__global__ __launch_bounds__(256)
void transw_kernel(const float* __restrict__ Wq, const float* __restrict__ Wk,
                   const float* __restrict__ Wv, const float* __restrict__ Wo,
                   u16* __restrict__ wt) {
  __shared__ float tile[32][33];
  const int z = blockIdx.z;
  const float* src = (z == 0) ? Wq
                   : (z <= 3) ? (Wk + (size_t)(z - 1) * 1048576)
                   : (z <= 6) ? (Wv + (size_t)(z - 4) * 1048576)
                              : Wo;
  u16* dst = wt + (size_t)z * 1048576;
  const int tx = threadIdx.x & 31, ty = threadIdx.x >> 5;
  const int bx = blockIdx.x * 32, by = blockIdx.y * 32;
#pragma unroll
  for (int i = 0; i < 4; ++i)
    tile[ty + i * 8][tx] = src[(size_t)(by + ty + i * 8) * 1024 + bx + tx];
  __syncthreads();
#pragma unroll
  for (int i = 0; i < 4; ++i)
    dst[(size_t)(bx + ty + i * 8) * 1024 + by + tx] = f2b(tile[tx][ty + i * 8]);
}

// ---------------------------------------------------------------------------
// GEMM: C[4096 x 1024] = A[4096,1024] * Bt[1024,1024]^T  (Bt row-major [n][k])
// 128x128 tile, BK=32, 256 thr = 4 waves (2x2), 4x4 16x16x32 MFMA frags/wave.
// KIND 0: projections z=0..6; z<4 token-major out via LDS-transposed 16B
//         stores; z>=4 (V) stored [b][h][d][n] via packed u16x4 stores.
// KIND 1: final GEMM split-K: z = K-half, f32 partial out.
// ---------------------------------------------------------------------------
template <int KIND>
__global__ __launch_bounds__(256)
void gemm_kernel(const u16* __restrict__ A, const u16* __restrict__ Bt,
                 void* __restrict__ Cout) {
  const int z = blockIdx.z;
  const int tid = threadIdx.x;
  const int w = tid >> 6, l = tid & 63;
  const int g = l >> 4, ll = l & 15;
  const int wr = w >> 1, wc = w & 1;
  const int m0 = blockIdx.y * 128, n0 = blockIdx.x * 128;

  const u16* Ab;
  const u16* Bb;
  if (KIND == 0) {
    Ab = A + (size_t)m0 * 1024;
    Bb = Bt + (size_t)z * 1048576 + (size_t)n0 * 1024;
  } else {  // split-K: z = K-half index
    Ab = A + (size_t)m0 * 1024 + z * 512;
    Bb = Bt + (size_t)n0 * 1024 + z * 512;
  }

  __shared__ u16 SH[4][4096];  // A dbuf = SH[0..1], B dbuf = SH[2..3] (32 KB)

  const f32x4 zero = {0.f, 0.f, 0.f, 0.f};
  f32x4 acc[4][4];
#pragma unroll
  for (int i = 0; i < 4; ++i)
#pragma unroll
    for (int j = 0; j < 4; ++j) acc[i][j] = zero;

  const int sr = l >> 2;        // row within 16-row segment
  const int sc = (l & 3) * 8;   // k-offset 0,8,16,24

  auto stage = [&](int buf, int t) {
    const int k0 = t * 32;
#pragma unroll
    for (int j = 0; j < 2; ++j) {
      const int seg = j * 4 + w;           // 8 segments x 512 elems
      const int r = seg * 16 + sr;
      gload16(Ab + (size_t)r * 1024 + k0 + sc, &SH[buf][seg * 512]);
      gload16(Bb + (size_t)r * 1024 + k0 + sc, &SH[2 + buf][seg * 512]);
    }
  };

  const int NT = (KIND == 1) ? 16 : 32;
  stage(0, 0);
  __syncthreads();
  int buf = 0;
  for (int t = 0; t < NT; ++t) {
    if (t < NT - 1) stage(buf ^ 1, t + 1);
    s16x8 af[4], bfr[4];
#pragma unroll
    for (int mf = 0; mf < 4; ++mf)
      af[mf] = *(const s16x8*)&SH[buf][(wr * 64 + mf * 16 + ll) * 32 + g * 8];
#pragma unroll
    for (int nf = 0; nf < 4; ++nf)
      bfr[nf] = *(const s16x8*)&SH[2 + buf][(wc * 64 + nf * 16 + ll) * 32 + g * 8];
#pragma unroll
    for (int mf = 0; mf < 4; ++mf)
#pragma unroll
      for (int nf = 0; nf < 4; ++nf)
        acc[mf][nf] = __builtin_amdgcn_mfma_f32_16x16x32_bf16(af[mf], bfr[nf],
                                                              acc[mf][nf], 0, 0, 0);
    __syncthreads();
    buf ^= 1;
  }

  if (KIND == 0) {
    u16* C = (u16*)Cout + (size_t)z * 4194304;
    if (z < 4) {
      // LDS tile-transpose (XOR-swizzled) -> 16B coalesced stores.
      u16* T = &SH[0][0];  // viewed as [128][128]
#pragma unroll
      for (int mf = 0; mf < 4; ++mf)
#pragma unroll
        for (int nf = 0; nf < 4; ++nf) {
          const int c = wc * 64 + nf * 16 + ll;
#pragma unroll
          for (int rg = 0; rg < 4; ++rg) {
            const int r = wr * 64 + mf * 16 + g * 4 + rg;
            T[r * 128 + (c ^ ((r & 7) << 4))] = f2b(acc[mf][nf][rg]);
          }
        }
      __syncthreads();
#pragma unroll
      for (int i = 0; i < 8; ++i) {
        const int R = (tid >> 4) + i * 16;
        const int c0 = (tid & 15) * 8;
        const s16x8 v = *(const s16x8*)&T[R * 128 + (c0 ^ ((R & 7) << 4))];
        *(s16x8*)&C[(size_t)(m0 + R) * 1024 + n0 + c0] = v;
      }
    } else {
      // V: lane's 4 rg-values are 4 consecutive tokens at fixed d -> u16x4.
#pragma unroll
      for (int mf = 0; mf < 4; ++mf)
#pragma unroll
        for (int nf = 0; nf < 4; ++nf) {
          const int col = n0 + wc * 64 + nf * 16 + ll;
          const int hh = col >> 6, d = col & 63;
          const int mb = m0 + wr * 64 + mf * 16 + g * 4;
          const int bb = mb >> 10, n = mb & 1023;
          u16x4 pk;
#pragma unroll
          for (int rg = 0; rg < 4; ++rg) pk[rg] = f2b(acc[mf][nf][rg]);
          *(u16x4*)&C[((size_t)((bb * 16 + hh) * 64 + d)) * 1024 + n] = pk;
        }
    }
  } else {
    float* C = (float*)Cout + (size_t)z * 4194304;
#pragma unroll
    for (int mf = 0; mf < 4; ++mf)
#pragma unroll
      for (int nf = 0; nf < 4; ++nf) {
        const int col = n0 + wc * 64 + nf * 16 + ll;
#pragma unroll
        for (int rg = 0; rg < 4; ++rg) {
          const int m = m0 + wr * 64 + mf * 16 + g * 4 + rg;
          C[(size_t)m * 1024 + col] = acc[mf][nf][rg];
        }
      }
  }
}

// ---------------------------------------------------------------------------
// reduce: out = P0 + P1 (f32, 4194304 elems)
// ---------------------------------------------------------------------------
__global__ __launch_bounds__(256)
void reduce_kernel(const float* __restrict__ P, float* __restrict__ out) {
  const int i = (blockIdx.x * 256 + threadIdx.x) * 4;
  const float4 a = *(const float4*)(P + i);
  const float4 b = *(const float4*)(P + 4194304 + i);
  float4 o;
  o.x = a.x + b.x; o.y = a.y + b.y; o.z = a.z + b.z; o.w = a.w + b.w;
  *(float4*)(out + i) = o;
}

// ---------------------------------------------------------------------------
// Fused causal flash attention (+optional SiLU epilogue), paired q-tiles.
// Q token-major (roped here); K token-major PRE-ROPED; Vt [(b*16+h)*64+d][n].
// Block handles q-tiles (p, 15-p) for one bh -> uniform 17 K-tiles of work.
// 512 blocks, XCD-swizzled so same-bh blocks share an XCD's L2.
// K double-buffered in LDS, T14 async-stage split (loads at loop top,
// ds_write after compute); V read direct from global (L2-resident).
// ---------------------------------------------------------------------------
template <int SILU>
__global__ __launch_bounds__(256)
void attn_kernel(const u16* __restrict__ Q, const u16* __restrict__ K,
                 const u16* __restrict__ Vt, u16* __restrict__ O,
                 const float* __restrict__ ct, const float* __restrict__ st) {
  const int lin = blockIdx.x + (blockIdx.y << 3);   // [0,512)
  const int role = (lin & 7) * 64 + (lin >> 3);     // bijective XCD swizzle
  const int p = role & 7, bh = role >> 3;
  const int q_lo = p, q_hi = 15 - p;
  const int b = bh >> 4, h = bh & 15;
  const int tid = threadIdx.x, w = tid >> 6, l = tid & 63;
  const int g = l >> 4, ll = l & 15;

  const u16* Qb = Q + (size_t)(b * 1024) * 1024 + h * 64;
  const u16* Kb = K + (size_t)(b * 1024) * 1024 + h * 64;
  const u16* Vb = Vt + (size_t)((b * 16 + h) * 64) * 1024;
  u16* Ob = O + (size_t)(b * 1024) * 1024 + h * 64;

  __shared__ u16 Ksh[2][64 * 72];   // [kpos][d] pre-roped, pad 72, dbuf
  __shared__ u16 Psh[4][16 * 72];   // per-wave P round-trip

  // --- Q fragments for both tiles: rope + 1/8 scale, A-layout ---
  s16x8 qfL[2], qfH[2];
  auto loadQ = [&](int qt, s16x8* qf) {
    const int qrow = qt * 64 + w * 16 + ll;
#pragma unroll
    for (int kc = 0; kc < 2; ++kc) {
      const int d0 = kc * 32 + g * 8;
      const int j0 = d0 >> 1;
      const float4 c4 = *(const float4*)(ct + qrow * 32 + j0);
      const float4 s4v = *(const float4*)(st + qrow * 32 + j0);
      const s16x8 qin = *(const s16x8*)(Qb + (size_t)qrow * 1024 + d0);
      s16x8 qo;
#pragma unroll
      for (int pp = 0; pp < 4; ++pp) {
        const float c = ((const float*)&c4)[pp], s = ((const float*)&s4v)[pp];
        const float x0 = b2f((u16)qin[2 * pp]), x1 = b2f((u16)qin[2 * pp + 1]);
        qo[2 * pp]     = (short)f2b((x0 * c - x1 * s) * 0.125f);
        qo[2 * pp + 1] = (short)f2b((x1 * c + x0 * s) * 0.125f);
      }
      qf[kc] = qo;
    }
  };
  loadQ(q_lo, qfL);
  loadQ(q_hi, qfH);

  float mL[4], lsL[4], mH[4], lsH[4];
  f32x4 oL[4], oH[4];
  const f32x4 zero = {0.f, 0.f, 0.f, 0.f};
#pragma unroll
  for (int rg = 0; rg < 4; ++rg) {
    mL[rg] = -3.0e38f; lsL[rg] = 0.f; mH[rg] = -3.0e38f; lsH[rg] = 0.f;
  }
#pragma unroll
  for (int df = 0; df < 4; ++df) { oL[df] = zero; oH[df] = zero; }

  const int srow = tid >> 2;        // 0..63
  const int sc0 = (tid & 3) * 16;   // 0,16,32,48

  s16x8 kr0, kr1;
  auto kload = [&](int t) {
    const u16* kp = Kb + (size_t)(t * 64 + srow) * 1024 + sc0;
    kr0 = *(const s16x8*)kp;
    kr1 = *(const s16x8*)(kp + 8);
  };
  auto kstore = [&](int bf) {
    *(s16x8*)&Ksh[bf][srow * 72 + sc0] = kr0;
    *(s16x8*)&Ksh[bf][srow * 72 + sc0 + 8] = kr1;
  };

  kload(0);
  kstore(0);
  __syncthreads();
  int buf = 0;

  for (int t = 0; t <= q_hi; ++t) {
    const bool pre = (t < q_hi);
    if (pre) kload(t + 1);            // issue loads early (T14)

    // V fragments direct from global (L2-resident), shared by both q-tiles
    s16x8 vb[2][4];
#pragma unroll
    for (int kc = 0; kc < 2; ++kc)
#pragma unroll
      for (int df = 0; df < 4; ++df)
        vb[kc][df] = *(const s16x8*)(Vb + (size_t)(df * 16 + ll) * 1024 +
                                     t * 64 + kc * 32 + g * 8);

    auto process = [&](const s16x8* qf, float* mm, float* ls, f32x4* o,
                       bool diag) {
      f32x4 s4[4];
      __builtin_amdgcn_s_setprio(1);
#pragma unroll
      for (int nf = 0; nf < 4; ++nf) {
        const s16x8 kb0 = *(const s16x8*)&Ksh[buf][(nf * 16 + ll) * 72 + g * 8];
        const s16x8 kb1 = *(const s16x8*)&Ksh[buf][(nf * 16 + ll) * 72 + 32 + g * 8];
        f32x4 sv = zero;
        sv = __builtin_amdgcn_mfma_f32_16x16x32_bf16(qf[0], kb0, sv, 0, 0, 0);
        sv = __builtin_amdgcn_mfma_f32_16x16x32_bf16(qf[1], kb1, sv, 0, 0, 0);
        s4[nf] = sv;
      }
      __builtin_amdgcn_s_setprio(0);

      if (diag) {  // causal mask inside diagonal tile (t == qt)
#pragma unroll
        for (int nf = 0; nf < 4; ++nf)
#pragma unroll
          for (int rg = 0; rg < 4; ++rg)
            if (nf * 16 + ll > w * 16 + g * 4 + rg) s4[nf][rg] = -3.0e38f;
      }

#pragma unroll
      for (int rg = 0; rg < 4; ++rg) {
        float rmax = fmaxf(fmaxf(s4[0][rg], s4[1][rg]),
                           fmaxf(s4[2][rg], s4[3][rg]));
        rmax = fmaxf(rmax, __shfl_xor(rmax, 1, 64));
        rmax = fmaxf(rmax, __shfl_xor(rmax, 2, 64));
        rmax = fmaxf(rmax, __shfl_xor(rmax, 4, 64));
        rmax = fmaxf(rmax, __shfl_xor(rmax, 8, 64));
        const float mn = fmaxf(mm[rg], rmax);
        const float scl = __expf(mm[rg] - mn);
        mm[rg] = mn;
        float ps = 0.f;
#pragma unroll
        for (int nf = 0; nf < 4; ++nf) {
          const float pv = __expf(s4[nf][rg] - mn);
          s4[nf][rg] = pv;
          ps += pv;
        }
        ls[rg] = ls[rg] * scl + ps;   // lane-partial; reduced at the end
#pragma unroll
        for (int df = 0; df < 4; ++df) o[df][rg] *= scl;
      }

#pragma unroll
      for (int nf = 0; nf < 4; ++nf)
#pragma unroll
        for (int rg = 0; rg < 4; ++rg)
          Psh[w][(g * 4 + rg) * 72 + nf * 16 + ll] = f2b(s4[nf][rg]);

      __builtin_amdgcn_s_setprio(1);
#pragma unroll
      for (int kc = 0; kc < 2; ++kc) {
        const s16x8 pa = *(const s16x8*)&Psh[w][ll * 72 + kc * 32 + g * 8];
#pragma unroll
        for (int df = 0; df < 4; ++df)
          o[df] = __builtin_amdgcn_mfma_f32_16x16x32_bf16(pa, vb[kc][df],
                                                          o[df], 0, 0, 0);
      }
      __builtin_amdgcn_s_setprio(0);
    };

    process(qfH, mH, lsH, oH, t == q_hi);
    if (t <= q_lo) process(qfL, mL, lsL, oL, t == q_lo);

    if (pre) kstore(buf ^ 1);         // vmcnt wait here, hidden under compute
    __syncthreads();
    buf ^= 1;
  }

  // ---- epilogue: normalize, optional SiLU, store token-major bf16 ----
  auto finish = [&](float* ls, f32x4* o, int qt) {
#pragma unroll
    for (int rg = 0; rg < 4; ++rg) {
      float v = ls[rg];
      v += __shfl_xor(v, 1, 64);
      v += __shfl_xor(v, 2, 64);
      v += __shfl_xor(v, 4, 64);
      v += __shfl_xor(v, 8, 64);
      ls[rg] = 1.f / v;
    }
#pragma unroll
    for (int df = 0; df < 4; ++df)
#pragma unroll
      for (int rg = 0; rg < 4; ++rg) {
        float val = o[df][rg] * ls[rg];
        if (SILU) val = val / (1.f + __expf(-val));
        Ob[(size_t)(qt * 64 + w * 16 + g * 4 + rg) * 1024 + df * 16 + ll] =
            f2b(val);
      }
  };
  finish(lsH, oH, q_hi);
  finish(lsL, oL, q_lo);
}

// ---------------------------------------------------------------------------
extern "C" void kernel_launch(void* const* d_in, const int* in_sizes, int n_in,
                              void* d_out, int out_size, void* d_ws, size_t ws_size,
                              hipStream_t stream) {
  (void)in_sizes; (void)n_in; (void)out_size; (void)ws_size;
  const float* tokens = (const float*)d_in[0];
  const float* gamma  = (const float*)d_in[1];
  const float* Wq     = (const float*)d_in[2];
  const float* Wk     = (const float*)d_in[3];
  const float* Wv     = (const float*)d_in[4];
  const float* Wo     = (const float*)d_in[5];
  float* out = (float*)d_out;

  // workspace layout (bf16 elems unless noted); total ~96.3 MB
  u16* x    = (u16*)d_ws;                       // [4096][1024]
  u16* wt   = x + (size_t)4096 * 1024;          // 8 x [1024][1024] transposed bf16
  u16* qkv  = wt + (size_t)8 * 1048576;         // Q,K0..2,V0..2 each [4096][1024]
  u16* outA = qkv + (size_t)7 * 4194304;        // attn out ping
  u16* outB = outA + 4194304;                   // attn out pong
  float* ct = (float*)(outB + 4194304);         // cos [1024][32]
  float* st = ct + 32768;                       // sin [1024][32]
  // split-K partials: reuse dead K/V slots (qkv slots 1..4) after attention
  float* Pp = (float*)(qkv + 1 * 4194304);      // 2 x [4096][1024] f32

  rmsnorm_kernel<<<4096, 256, 0, stream>>>(tokens, gamma, x);
  rope_kernel<<<128, 256, 0, stream>>>(ct, st);
  transw_kernel<<<dim3(32, 32, 8), 256, 0, stream>>>(Wq, Wk, Wv, Wo, wt);
  gemm_kernel<0><<<dim3(8, 32, 7), 256, 0, stream>>>(x, wt, qkv);

  const size_t M4 = 4194304;
  ropek_kernel<<<dim3(4096, 3), 256, 0, stream>>>(qkv + M4, ct, st);

  attn_kernel<1><<<dim3(8, 64), 256, 0, stream>>>(qkv, qkv + 1 * M4, qkv + 4 * M4,
                                                  outA, ct, st);
  attn_kernel<1><<<dim3(8, 64), 256, 0, stream>>>(outA, qkv + 2 * M4, qkv + 5 * M4,
                                                  outB, ct, st);
  attn_kernel<0><<<dim3(8, 64), 256, 0, stream>>>(outB, qkv + 3 * M4, qkv + 6 * M4,
                                                  outA, ct, st);

  gemm_kernel<1><<<dim3(8, 32, 2), 256, 0, stream>>>(outA, wt + (size_t)7 * 1048576,
                                                     (void*)Pp);
  reduce_kernel<<<4096, 256, 0, stream>>>(Pp, out);
}

// Round 4
// 253.981 us; speedup vs baseline: 1.3482x; 1.0342x over previous
//
#include <hip/hip_runtime.h>

// ---------------------------------------------------------------------------
// ImplicitMLPAttention: B=4, N=1024, D=1024, H=16, DH=64, 3 attention layers.
// RMSNorm -> 7 projection GEMMs (bf16 MFMA, ring-4 counted-vmcnt pipeline) ->
// pre-rope K -> 3x fused causal flash-attention (paired q-tiles, +SiLU) ->
// final GEMM (split-K2, f32) -> reduce.
// ---------------------------------------------------------------------------

typedef unsigned short u16;
typedef short s16x8 __attribute__((ext_vector_type(8)));
typedef u16 u16x4 __attribute__((ext_vector_type(4)));
typedef float f32x4 __attribute__((ext_vector_type(4)));

typedef __attribute__((address_space(1))) const unsigned int as1c_uint;
typedef __attribute__((address_space(3))) unsigned int as3_uint;

__device__ __forceinline__ float b2f(u16 h) {
  union { unsigned int u; float f; } v; v.u = ((unsigned int)h) << 16; return v.f;
}
__device__ __forceinline__ u16 f2b(float f) {
  union { float f; unsigned int u; } v; v.f = f;
  return (u16)((v.u + 0x7FFFu + ((v.u >> 16) & 1u)) >> 16);
}
// async global->LDS, 16B per lane. LDS dest must be wave-uniform base (+lane*16 in HW).
__device__ __forceinline__ void gload16(const u16* g, const u16* lds) {
  __builtin_amdgcn_global_load_lds((as1c_uint*)(size_t)g,
                                   (as3_uint*)(unsigned int)(size_t)lds, 16, 0, 0);
}

// ---------------------------------------------------------------------------
// RMSNorm: tokens f32 [4096,1024] -> x bf16, * gamma
// ---------------------------------------------------------------------------
__global__ __launch_bounds__(256)
void rmsnorm_kernel(const float* __restrict__ T, const float* __restrict__ gamma,
                    u16* __restrict__ X) {
  const int row = blockIdx.x, tid = threadIdx.x;
  const float4 v = ((const float4*)(T + (size_t)row * 1024))[tid];
  float ss = v.x * v.x + v.y * v.y + v.z * v.z + v.w * v.w;
#pragma unroll
  for (int msk = 1; msk <= 32; msk <<= 1) ss += __shfl_xor(ss, msk, 64);
  __shared__ float red[4];
  if ((tid & 63) == 0) red[tid >> 6] = ss;
  __syncthreads();
  const float tot = red[0] + red[1] + red[2] + red[3];
  const float r = rsqrtf(tot * (1.0f / 1024.0f) + 1.1920929e-07f);
  const float4 gm = ((const float4*)gamma)[tid];
  u16x4 o;
  o[0] = f2b(v.x * r * gm.x); o[1] = f2b(v.y * r * gm.y);
  o[2] = f2b(v.z * r * gm.z); o[3] = f2b(v.w * r * gm.w);
  *(u16x4*)(X + (size_t)row * 1024 + tid * 4) = o;
}

// ---------------------------------------------------------------------------
// RoPE tables: cos/sin [1024][32] f32 (theta=10000, interleaved pairs)
// ---------------------------------------------------------------------------
__global__ __launch_bounds__(256)
void rope_kernel(float* __restrict__ ct, float* __restrict__ st) {
  const int idx = blockIdx.x * 256 + threadIdx.x;  // 32768
  const int n = idx >> 5, j = idx & 31;
  const double freq = pow(10000.0, -(double)j / 32.0);
  const double a = (double)n * freq;
  ct[idx] = (float)cos(a);
  st[idx] = (float)sin(a);
}

// ---------------------------------------------------------------------------
// Pre-rope K in place: 3 buffers of [4096][1024] bf16, token-major.
// ---------------------------------------------------------------------------
__global__ __launch_bounds__(256)
void ropek_kernel(u16* __restrict__ K, const float* __restrict__ ct,
                  const float* __restrict__ st) {
  u16* row = K + (size_t)blockIdx.y * 4194304 + (size_t)blockIdx.x * 1024;
  const int n = blockIdx.x & 1023;
  const int t = threadIdx.x;
  const int j = ((t * 4) & 63) >> 1;  // even pair index within head
  const float2 c2 = *(const float2*)(ct + n * 32 + j);
  const float2 s2 = *(const float2*)(st + n * 32 + j);
  u16x4 v = *(u16x4*)(row + t * 4);
  const float x0 = b2f(v[0]), x1 = b2f(v[1]);
  const float y0 = b2f(v[2]), y1 = b2f(v[3]);
  u16x4 o;
  o[0] = f2b(x0 * c2.x - x1 * s2.x);
  o[1] = f2b(x1 * c2.x + x0 * s2.x);
  o[2] = f2b(y0 * c2.y - y1 * s2.y);
  o[3] = f2b(y1 * c2.y + y0 * s2.y);
  *(u16x4*)(row + t * 4) = o;
}

// ---------------------------------------------------------------------------
// Weight transpose + bf16 cast: wt[z][n][k] = bf16(W_z[k][n]), z in 0..7
// ---------------------------------------------------------------------------
__global__ __launch_bounds__(256)
void transw_kernel(const float* __restrict__ Wq, const float* __restrict__ Wk,
                   const float* __restrict__ Wv, const float* __restrict__ Wo,
                   u16* __restrict__ wt) {
  __shared__ float tile[32][33];
  const int z = blockIdx.z;
  const float* src = (z == 0) ? Wq
                   : (z <= 3) ? (Wk + (size_t)(z - 1) * 1048576)
                   : (z <= 6) ? (Wv + (size_t)(z - 4) * 1048576)
                              : Wo;
  u16* dst = wt + (size_t)z * 1048576;
  const int tx = threadIdx.x & 31, ty = threadIdx.x >> 5;
  const int bx = blockIdx.x * 32, by = blockIdx.y * 32;
#pragma unroll
  for (int i = 0; i < 4; ++i)
    tile[ty + i * 8][tx] = src[(size_t)(by + ty + i * 8) * 1024 + bx + tx];
  __syncthreads();
#pragma unroll
  for (int i = 0; i < 4; ++i)
    dst[(size_t)(bx + ty + i * 8) * 1024 + by + tx] = f2b(tile[tx][ty + i * 8]);
}

// ---------------------------------------------------------------------------
// GEMM: C[4096 x 1024] = A[4096,1024] * Bt[1024,1024]^T  (Bt row-major [n][k])
// 128x128 tile, BK=32, 256 thr = 4 waves (2x2), 4x4 16x16x32 MFMA frags/wave.
// Ring-4 LDS pipeline (stage t+3 during t), ONE raw s_barrier per K-step,
// counted vmcnt (8/4/0) -- never a full drain in steady state.
// T2 swizzle: LDS 16B-slot ^= (row>>1)&3, with inverse-swizzled global source
// (global_load_lds dest stays linear per m104).
// KIND 0: projections z=0..6; z<4 token-major out via LDS-transposed 16B
//         stores; z>=4 (V) stored [b][h][d][n] via packed u16x4 stores.
// KIND 1: final GEMM split-K: z = K-half, f32 partial out.
// ---------------------------------------------------------------------------
template <int KIND>
__global__ __launch_bounds__(256)
void gemm_kernel(const u16* __restrict__ A, const u16* __restrict__ Bt,
                 void* __restrict__ Cout) {
  const int z = blockIdx.z;
  const int tid = threadIdx.x;
  const int w = tid >> 6, l = tid & 63;
  const int g = l >> 4, ll = l & 15;
  const int wr = w >> 1, wc = w & 1;
  const int m0 = blockIdx.y * 128, n0 = blockIdx.x * 128;

  const u16* Ab;
  const u16* Bb;
  if (KIND == 0) {
    Ab = A + (size_t)m0 * 1024;
    Bb = Bt + (size_t)z * 1048576 + (size_t)n0 * 1024;
  } else {  // split-K: z = K-half index
    Ab = A + (size_t)m0 * 1024 + z * 512;
    Bb = Bt + (size_t)n0 * 1024 + z * 512;
  }

  // ring-4: slot s -> A tile at SH[s][0..4095], B tile at SH[s][4096..8191]
  __shared__ u16 SH[4][8192];  // 64 KB

  const f32x4 zero = {0.f, 0.f, 0.f, 0.f};
  f32x4 acc[4][4];
#pragma unroll
  for (int i = 0; i < 4; ++i)
#pragma unroll
    for (int j = 0; j < 4; ++j) acc[i][j] = zero;

  // stage tile t2: per wave 2 chunks of 1KB each for A and B.
  // linear LDS dest; source k-slot pre-swizzled: slg = sl ^ ((row>>1)&3)
  auto stage = [&](int t2) {
    const int slot = t2 & 3;
    const int k0 = t2 * 32;
#pragma unroll
    for (int c = 0; c < 2; ++c) {
      const int chunk = c * 4 + w;               // 8 chunks x 16 rows
      const int row = chunk * 16 + (l >> 2);
      const int sl = l & 3;
      const int kk = k0 + ((sl ^ ((row >> 1) & 3)) << 3);
      gload16(Ab + (size_t)row * 1024 + kk, &SH[slot][chunk * 512]);
      gload16(Bb + (size_t)row * 1024 + kk, &SH[slot][4096 + chunk * 512]);
    }
  };

  const int NT = (KIND == 1) ? 16 : 32;
  stage(0); stage(1); stage(2);

#pragma unroll
  for (int t = 0; t < NT; ++t) {
    // force own loads for tile t landed; allow newest (beyond-t) tiles in flight
    const int beyond = (NT - 1) - t;
    if (beyond >= 2)      asm volatile("s_waitcnt vmcnt(8)" ::: "memory");
    else if (beyond == 1) asm volatile("s_waitcnt vmcnt(4)" ::: "memory");
    else                  asm volatile("s_waitcnt vmcnt(0)" ::: "memory");
    __builtin_amdgcn_s_barrier();   // now tile t is fully in LDS (all waves)

    const int slot = t & 3;
    const u16* As = &SH[slot][0];
    const u16* Bs = &SH[slot][4096];
    s16x8 af[4], bfr[4];
#pragma unroll
    for (int mf = 0; mf < 4; ++mf) {
      const int row = wr * 64 + mf * 16 + ll;
      af[mf] = *(const s16x8*)&As[row * 32 + ((g ^ ((row >> 1) & 3)) << 3)];
    }
#pragma unroll
    for (int nf = 0; nf < 4; ++nf) {
      const int row = wc * 64 + nf * 16 + ll;
      bfr[nf] = *(const s16x8*)&Bs[row * 32 + ((g ^ ((row >> 1) & 3)) << 3)];
    }

    if (t + 3 < NT) stage(t + 3);   // overwrites slot (t-1)&3: reads done

    __builtin_amdgcn_s_setprio(1);
#pragma unroll
    for (int mf = 0; mf < 4; ++mf)
#pragma unroll
      for (int nf = 0; nf < 4; ++nf)
        acc[mf][nf] = __builtin_amdgcn_mfma_f32_16x16x32_bf16(af[mf], bfr[nf],
                                                              acc[mf][nf], 0, 0, 0);
    __builtin_amdgcn_s_setprio(0);
  }
  __syncthreads();  // epilogue may reuse LDS

  if (KIND == 0) {
    u16* C = (u16*)Cout + (size_t)z * 4194304;
    if (z < 4) {
      // LDS tile-transpose (XOR-swizzled) -> 16B coalesced stores.
      u16* T = &SH[0][0];  // viewed as [128][128]
#pragma unroll
      for (int mf = 0; mf < 4; ++mf)
#pragma unroll
        for (int nf = 0; nf < 4; ++nf) {
          const int c = wc * 64 + nf * 16 + ll;
#pragma unroll
          for (int rg = 0; rg < 4; ++rg) {
            const int r = wr * 64 + mf * 16 + g * 4 + rg;
            T[r * 128 + (c ^ ((r & 7) << 4))] = f2b(acc[mf][nf][rg]);
          }
        }
      __syncthreads();
#pragma unroll
      for (int i = 0; i < 8; ++i) {
        const int R = (tid >> 4) + i * 16;
        const int c0 = (tid & 15) * 8;
        const s16x8 v = *(const s16x8*)&T[R * 128 + (c0 ^ ((R & 7) << 4))];
        *(s16x8*)&C[(size_t)(m0 + R) * 1024 + n0 + c0] = v;
      }
    } else {
      // V: lane's 4 rg-values are 4 consecutive tokens at fixed d -> u16x4.
#pragma unroll
      for (int mf = 0; mf < 4; ++mf)
#pragma unroll
        for (int nf = 0; nf < 4; ++nf) {
          const int col = n0 + wc * 64 + nf * 16 + ll;
          const int hh = col >> 6, d = col & 63;
          const int mb = m0 + wr * 64 + mf * 16 + g * 4;
          const int bb = mb >> 10, n = mb & 1023;
          u16x4 pk;
#pragma unroll
          for (int rg = 0; rg < 4; ++rg) pk[rg] = f2b(acc[mf][nf][rg]);
          *(u16x4*)&C[((size_t)((bb * 16 + hh) * 64 + d)) * 1024 + n] = pk;
        }
    }
  } else {
    float* C = (float*)Cout + (size_t)z * 4194304;
#pragma unroll
    for (int mf = 0; mf < 4; ++mf)
#pragma unroll
      for (int nf = 0; nf < 4; ++nf) {
        const int col = n0 + wc * 64 + nf * 16 + ll;
#pragma unroll
        for (int rg = 0; rg < 4; ++rg) {
          const int m = m0 + wr * 64 + mf * 16 + g * 4 + rg;
          C[(size_t)m * 1024 + col] = acc[mf][nf][rg];
        }
      }
  }
}

// ---------------------------------------------------------------------------
// reduce: out = P0 + P1 (f32, 4194304 elems)
// ---------------------------------------------------------------------------
__global__ __launch_bounds__(256)
void reduce_kernel(const float* __restrict__ P, float* __restrict__ out) {
  const int i = (blockIdx.x * 256 + threadIdx.x) * 4;
  const float4 a = *(const float4*)(P + i);
  const float4 b = *(const float4*)(P + 4194304 + i);
  float4 o;
  o.x = a.x + b.x; o.y = a.y + b.y; o.z = a.z + b.z; o.w = a.w + b.w;
  *(float4*)(out + i) = o;
}

// ---------------------------------------------------------------------------
// Fused causal flash attention (+optional SiLU epilogue), paired q-tiles.
// Q token-major (roped here); K token-major PRE-ROPED; Vt [(b*16+h)*64+d][n].
// Block handles q-tiles (p, 15-p) for one bh -> uniform 17 K-tiles of work.
// ---------------------------------------------------------------------------
template <int SILU>
__global__ __launch_bounds__(256)
void attn_kernel(const u16* __restrict__ Q, const u16* __restrict__ K,
                 const u16* __restrict__ Vt, u16* __restrict__ O,
                 const float* __restrict__ ct, const float* __restrict__ st) {
  const int lin = blockIdx.x + (blockIdx.y << 3);   // [0,512)
  const int role = (lin & 7) * 64 + (lin >> 3);     // bijective XCD swizzle
  const int p = role & 7, bh = role >> 3;
  const int q_lo = p, q_hi = 15 - p;
  const int b = bh >> 4, h = bh & 15;
  const int tid = threadIdx.x, w = tid >> 6, l = tid & 63;
  const int g = l >> 4, ll = l & 15;

  const u16* Qb = Q + (size_t)(b * 1024) * 1024 + h * 64;
  const u16* Kb = K + (size_t)(b * 1024) * 1024 + h * 64;
  const u16* Vb = Vt + (size_t)((b * 16 + h) * 64) * 1024;
  u16* Ob = O + (size_t)(b * 1024) * 1024 + h * 64;

  __shared__ u16 Ksh[2][64 * 72];   // [kpos][d] pre-roped, pad 72, dbuf
  __shared__ u16 Psh[4][16 * 72];   // per-wave P round-trip

  // --- Q fragments for both tiles: rope + 1/8 scale, A-layout ---
  s16x8 qfL[2], qfH[2];
  auto loadQ = [&](int qt, s16x8* qf) {
    const int qrow = qt * 64 + w * 16 + ll;
#pragma unroll
    for (int kc = 0; kc < 2; ++kc) {
      const int d0 = kc * 32 + g * 8;
      const int j0 = d0 >> 1;
      const float4 c4 = *(const float4*)(ct + qrow * 32 + j0);
      const float4 s4v = *(const float4*)(st + qrow * 32 + j0);
      const s16x8 qin = *(const s16x8*)(Qb + (size_t)qrow * 1024 + d0);
      s16x8 qo;
#pragma unroll
      for (int pp = 0; pp < 4; ++pp) {
        const float c = ((const float*)&c4)[pp], s = ((const float*)&s4v)[pp];
        const float x0 = b2f((u16)qin[2 * pp]), x1 = b2f((u16)qin[2 * pp + 1]);
        qo[2 * pp]     = (short)f2b((x0 * c - x1 * s) * 0.125f);
        qo[2 * pp + 1] = (short)f2b((x1 * c + x0 * s) * 0.125f);
      }
      qf[kc] = qo;
    }
  };
  loadQ(q_lo, qfL);
  loadQ(q_hi, qfH);

  float mL[4], lsL[4], mH[4], lsH[4];
  f32x4 oL[4], oH[4];
  const f32x4 zero = {0.f, 0.f, 0.f, 0.f};
#pragma unroll
  for (int rg = 0; rg < 4; ++rg) {
    mL[rg] = -3.0e38f; lsL[rg] = 0.f; mH[rg] = -3.0e38f; lsH[rg] = 0.f;
  }
#pragma unroll
  for (int df = 0; df < 4; ++df) { oL[df] = zero; oH[df] = zero; }

  const int srow = tid >> 2;        // 0..63
  const int sc0 = (tid & 3) * 16;   // 0,16,32,48

  s16x8 kr0, kr1;
  auto kload = [&](int t) {
    const u16* kp = Kb + (size_t)(t * 64 + srow) * 1024 + sc0;
    kr0 = *(const s16x8*)kp;
    kr1 = *(const s16x8*)(kp + 8);
  };
  auto kstore = [&](int bf) {
    *(s16x8*)&Ksh[bf][srow * 72 + sc0] = kr0;
    *(s16x8*)&Ksh[bf][srow * 72 + sc0 + 8] = kr1;
  };

  kload(0);
  kstore(0);
  __syncthreads();
  int buf = 0;

  for (int t = 0; t <= q_hi; ++t) {
    const bool pre = (t < q_hi);
    if (pre) kload(t + 1);            // issue loads early (T14)

    // V fragments direct from global (L2-resident), shared by both q-tiles
    s16x8 vb[2][4];
#pragma unroll
    for (int kc = 0; kc < 2; ++kc)
#pragma unroll
      for (int df = 0; df < 4; ++df)
        vb[kc][df] = *(const s16x8*)(Vb + (size_t)(df * 16 + ll) * 1024 +
                                     t * 64 + kc * 32 + g * 8);

    auto process = [&](const s16x8* qf, float* mm, float* ls, f32x4* o,
                       bool diag) {
      f32x4 s4[4];
      __builtin_amdgcn_s_setprio(1);
#pragma unroll
      for (int nf = 0; nf < 4; ++nf) {
        const s16x8 kb0 = *(const s16x8*)&Ksh[buf][(nf * 16 + ll) * 72 + g * 8];
        const s16x8 kb1 = *(const s16x8*)&Ksh[buf][(nf * 16 + ll) * 72 + 32 + g * 8];
        f32x4 sv = zero;
        sv = __builtin_amdgcn_mfma_f32_16x16x32_bf16(qf[0], kb0, sv, 0, 0, 0);
        sv = __builtin_amdgcn_mfma_f32_16x16x32_bf16(qf[1], kb1, sv, 0, 0, 0);
        s4[nf] = sv;
      }
      __builtin_amdgcn_s_setprio(0);

      if (diag) {  // causal mask inside diagonal tile (t == qt)
#pragma unroll
        for (int nf = 0; nf < 4; ++nf)
#pragma unroll
          for (int rg = 0; rg < 4; ++rg)
            if (nf * 16 + ll > w * 16 + g * 4 + rg) s4[nf][rg] = -3.0e38f;
      }

#pragma unroll
      for (int rg = 0; rg < 4; ++rg) {
        float rmax = fmaxf(fmaxf(s4[0][rg], s4[1][rg]),
                           fmaxf(s4[2][rg], s4[3][rg]));
        rmax = fmaxf(rmax, __shfl_xor(rmax, 1, 64));
        rmax = fmaxf(rmax, __shfl_xor(rmax, 2, 64));
        rmax = fmaxf(rmax, __shfl_xor(rmax, 4, 64));
        rmax = fmaxf(rmax, __shfl_xor(rmax, 8, 64));
        const float mn = fmaxf(mm[rg], rmax);
        const float scl = __expf(mm[rg] - mn);
        mm[rg] = mn;
        float ps = 0.f;
#pragma unroll
        for (int nf = 0; nf < 4; ++nf) {
          const float pv = __expf(s4[nf][rg] - mn);
          s4[nf][rg] = pv;
          ps += pv;
        }
        ls[rg] = ls[rg] * scl + ps;   // lane-partial; reduced at the end
#pragma unroll
        for (int df = 0; df < 4; ++df) o[df][rg] *= scl;
      }

#pragma unroll
      for (int nf = 0; nf < 4; ++nf)
#pragma unroll
        for (int rg = 0; rg < 4; ++rg)
          Psh[w][(g * 4 + rg) * 72 + nf * 16 + ll] = f2b(s4[nf][rg]);

      __builtin_amdgcn_s_setprio(1);
#pragma unroll
      for (int kc = 0; kc < 2; ++kc) {
        const s16x8 pa = *(const s16x8*)&Psh[w][ll * 72 + kc * 32 + g * 8];
#pragma unroll
        for (int df = 0; df < 4; ++df)
          o[df] = __builtin_amdgcn_mfma_f32_16x16x32_bf16(pa, vb[kc][df],
                                                          o[df], 0, 0, 0);
      }
      __builtin_amdgcn_s_setprio(0);
    };

    process(qfH, mH, lsH, oH, t == q_hi);
    if (t <= q_lo) process(qfL, mL, lsL, oL, t == q_lo);

    if (pre) kstore(buf ^ 1);         // vmcnt wait here, hidden under compute
    __syncthreads();
    buf ^= 1;
  }

  // ---- epilogue: normalize, optional SiLU, store token-major bf16 ----
  auto finish = [&](float* ls, f32x4* o, int qt) {
#pragma unroll
    for (int rg = 0; rg < 4; ++rg) {
      float v = ls[rg];
      v += __shfl_xor(v, 1, 64);
      v += __shfl_xor(v, 2, 64);
      v += __shfl_xor(v, 4, 64);
      v += __shfl_xor(v, 8, 64);
      ls[rg] = 1.f / v;
    }
#pragma unroll
    for (int df = 0; df < 4; ++df)
#pragma unroll
      for (int rg = 0; rg < 4; ++rg) {
        float val = o[df][rg] * ls[rg];
        if (SILU) val = val / (1.f + __expf(-val));
        Ob[(size_t)(qt * 64 + w * 16 + g * 4 + rg) * 1024 + df * 16 + ll] =
            f2b(val);
      }
  };
  finish(lsH, oH, q_hi);
  finish(lsL, oL, q_lo);
}

// ---------------------------------------------------------------------------
extern "C" void kernel_launch(void* const* d_in, const int* in_sizes, int n_in,
                              void* d_out, int out_size, void* d_ws, size_t ws_size,
                              hipStream_t stream) {
  (void)in_sizes; (void)n_in; (void)out_size; (void)ws_size;
  const float* tokens = (const float*)d_in[0];
  const float* gamma  = (const float*)d_in[1];
  const float* Wq     = (const float*)d_in[2];
  const float* Wk     = (const float*)d_in[3];
  const float* Wv     = (const float*)d_in[4];
  const float* Wo     = (const float*)d_in[5];
  float* out = (float*)d_out;

  // workspace layout (bf16 elems unless noted); total ~96.3 MB
  u16* x    = (u16*)d_ws;                       // [4096][1024]
  u16* wt   = x + (size_t)4096 * 1024;          // 8 x [1024][1024] transposed bf16
  u16* qkv  = wt + (size_t)8 * 1048576;         // Q,K0..2,V0..2 each [4096][1024]
  u16* outA = qkv + (size_t)7 * 4194304;        // attn out ping
  u16* outB = outA + 4194304;                   // attn out pong
  float* ct = (float*)(outB + 4194304);         // cos [1024][32]
  float* st = ct + 32768;                       // sin [1024][32]
  // split-K partials: reuse dead K/V slots (qkv slots 1..4) after attention
  float* Pp = (float*)(qkv + 1 * 4194304);      // 2 x [4096][1024] f32

  rmsnorm_kernel<<<4096, 256, 0, stream>>>(tokens, gamma, x);
  rope_kernel<<<128, 256, 0, stream>>>(ct, st);
  transw_kernel<<<dim3(32, 32, 8), 256, 0, stream>>>(Wq, Wk, Wv, Wo, wt);
  gemm_kernel<0><<<dim3(8, 32, 7), 256, 0, stream>>>(x, wt, qkv);

  const size_t M4 = 4194304;
  ropek_kernel<<<dim3(4096, 3), 256, 0, stream>>>(qkv + M4, ct, st);

  attn_kernel<1><<<dim3(8, 64), 256, 0, stream>>>(qkv, qkv + 1 * M4, qkv + 4 * M4,
                                                  outA, ct, st);
  attn_kernel<1><<<dim3(8, 64), 256, 0, stream>>>(outA, qkv + 2 * M4, qkv + 5 * M4,
                                                  outB, ct, st);
  attn_kernel<0><<<dim3(8, 64), 256, 0, stream>>>(outB, qkv + 3 * M4, qkv + 6 * M4,
                                                  outA, ct, st);

  gemm_kernel<1><<<dim3(8, 32, 2), 256, 0, stream>>>(outA, wt + (size_t)7 * 1048576,
                                                     (void*)Pp);
  reduce_kernel<<<4096, 256, 0, stream>>>(Pp, out);
}

// Round 5
// 239.472 us; speedup vs baseline: 1.4298x; 1.0606x over previous
//
#include <hip/hip_runtime.h>

// ---------------------------------------------------------------------------
// ImplicitMLPAttention: B=4, N=1024, D=1024, H=16, DH=64, 3 attention layers.
// RMSNorm -> 7 projection GEMMs (bf16 MFMA, ring-4 counted-vmcnt pipeline,
// XCD-locality block ordering) -> pre-rope K -> 3x fused causal
// flash-attention (paired q-tiles, +SiLU) -> final GEMM (split-K2) -> reduce.
// ---------------------------------------------------------------------------

typedef unsigned short u16;
typedef short s16x8 __attribute__((ext_vector_type(8)));
typedef u16 u16x4 __attribute__((ext_vector_type(4)));
typedef float f32x4 __attribute__((ext_vector_type(4)));

typedef __attribute__((address_space(1))) const unsigned int as1c_uint;
typedef __attribute__((address_space(3))) unsigned int as3_uint;

__device__ __forceinline__ float b2f(u16 h) {
  union { unsigned int u; float f; } v; v.u = ((unsigned int)h) << 16; return v.f;
}
__device__ __forceinline__ u16 f2b(float f) {
  union { float f; unsigned int u; } v; v.f = f;
  return (u16)((v.u + 0x7FFFu + ((v.u >> 16) & 1u)) >> 16);
}
// async global->LDS, 16B per lane. LDS dest must be wave-uniform base (+lane*16 in HW).
__device__ __forceinline__ void gload16(const u16* g, const u16* lds) {
  __builtin_amdgcn_global_load_lds((as1c_uint*)(size_t)g,
                                   (as3_uint*)(unsigned int)(size_t)lds, 16, 0, 0);
}

// ---------------------------------------------------------------------------
// RMSNorm: tokens f32 [4096,1024] -> x bf16, * gamma
// ---------------------------------------------------------------------------
__global__ __launch_bounds__(256)
void rmsnorm_kernel(const float* __restrict__ T, const float* __restrict__ gamma,
                    u16* __restrict__ X) {
  const int row = blockIdx.x, tid = threadIdx.x;
  const float4 v = ((const float4*)(T + (size_t)row * 1024))[tid];
  float ss = v.x * v.x + v.y * v.y + v.z * v.z + v.w * v.w;
#pragma unroll
  for (int msk = 1; msk <= 32; msk <<= 1) ss += __shfl_xor(ss, msk, 64);
  __shared__ float red[4];
  if ((tid & 63) == 0) red[tid >> 6] = ss;
  __syncthreads();
  const float tot = red[0] + red[1] + red[2] + red[3];
  const float r = rsqrtf(tot * (1.0f / 1024.0f) + 1.1920929e-07f);
  const float4 gm = ((const float4*)gamma)[tid];
  u16x4 o;
  o[0] = f2b(v.x * r * gm.x); o[1] = f2b(v.y * r * gm.y);
  o[2] = f2b(v.z * r * gm.z); o[3] = f2b(v.w * r * gm.w);
  *(u16x4*)(X + (size_t)row * 1024 + tid * 4) = o;
}

// ---------------------------------------------------------------------------
// RoPE tables: cos/sin [1024][32] f32 (theta=10000, interleaved pairs)
// ---------------------------------------------------------------------------
__global__ __launch_bounds__(256)
void rope_kernel(float* __restrict__ ct, float* __restrict__ st) {
  const int idx = blockIdx.x * 256 + threadIdx.x;  // 32768
  const int n = idx >> 5, j = idx & 31;
  const double freq = pow(10000.0, -(double)j / 32.0);
  const double a = (double)n * freq;
  ct[idx] = (float)cos(a);
  st[idx] = (float)sin(a);
}

// ---------------------------------------------------------------------------
// Pre-rope K in place: 3 buffers of [4096][1024] bf16, token-major.
// ---------------------------------------------------------------------------
__global__ __launch_bounds__(256)
void ropek_kernel(u16* __restrict__ K, const float* __restrict__ ct,
                  const float* __restrict__ st) {
  u16* row = K + (size_t)blockIdx.y * 4194304 + (size_t)blockIdx.x * 1024;
  const int n = blockIdx.x & 1023;
  const int t = threadIdx.x;
  const int j = ((t * 4) & 63) >> 1;  // even pair index within head
  const float2 c2 = *(const float2*)(ct + n * 32 + j);
  const float2 s2 = *(const float2*)(st + n * 32 + j);
  u16x4 v = *(u16x4*)(row + t * 4);
  const float x0 = b2f(v[0]), x1 = b2f(v[1]);
  const float y0 = b2f(v[2]), y1 = b2f(v[3]);
  u16x4 o;
  o[0] = f2b(x0 * c2.x - x1 * s2.x);
  o[1] = f2b(x1 * c2.x + x0 * s2.x);
  o[2] = f2b(y0 * c2.y - y1 * s2.y);
  o[3] = f2b(y1 * c2.y + y0 * s2.y);
  *(u16x4*)(row + t * 4) = o;
}

// ---------------------------------------------------------------------------
// Weight transpose + bf16 cast: wt[z][n][k] = bf16(W_z[k][n]), z in 0..7
// ---------------------------------------------------------------------------
__global__ __launch_bounds__(256)
void transw_kernel(const float* __restrict__ Wq, const float* __restrict__ Wk,
                   const float* __restrict__ Wv, const float* __restrict__ Wo,
                   u16* __restrict__ wt) {
  __shared__ float tile[32][33];
  const int z = blockIdx.z;
  const float* src = (z == 0) ? Wq
                   : (z <= 3) ? (Wk + (size_t)(z - 1) * 1048576)
                   : (z <= 6) ? (Wv + (size_t)(z - 4) * 1048576)
                              : Wo;
  u16* dst = wt + (size_t)z * 1048576;
  const int tx = threadIdx.x & 31, ty = threadIdx.x >> 5;
  const int bx = blockIdx.x * 32, by = blockIdx.y * 32;
#pragma unroll
  for (int i = 0; i < 4; ++i)
    tile[ty + i * 8][tx] = src[(size_t)(by + ty + i * 8) * 1024 + bx + tx];
  __syncthreads();
#pragma unroll
  for (int i = 0; i < 4; ++i)
    dst[(size_t)(bx + ty + i * 8) * 1024 + by + tx] = f2b(tile[tx][ty + i * 8]);
}

// ---------------------------------------------------------------------------
// GEMM: C[4096 x 1024] = A[4096,1024] * Bt[1024,1024]^T  (Bt row-major [n][k])
// 128x128 tile, BK=32, 256 thr = 4 waves (2x2), 4x4 16x16x32 MFMA frags/wave.
// Ring-4 LDS pipeline, ONE raw s_barrier per K-step, counted vmcnt.
// XCD-locality 1-D grid: physical p -> XCD p%8; XCD i gets contiguous role
// chunk, roles z-major then m-outer/n-inner, so each XCD keeps its z's B
// matrix (2 MB) L2-resident and reuses each 256 KB A-tile across 8 n-blocks.
// KIND 0: projections z=0..6 (1792 roles, chunk 224); z<4 token-major out via
//         LDS-transpose; z>=4 (V) stored [b][h][d][n] packed u16x4.
// KIND 1: final GEMM split-K (512 roles, chunk 64): z = K-half, f32 partials.
// ---------------------------------------------------------------------------
template <int KIND>
__global__ __launch_bounds__(256)
void gemm_kernel(const u16* __restrict__ A, const u16* __restrict__ Bt,
                 void* __restrict__ Cout) {
  const int p = blockIdx.x;
  const int role = (p & 7) * (KIND == 0 ? 224 : 64) + (p >> 3);
  const int z = role >> 8;
  const int rem = role & 255;
  const int m0 = (rem >> 3) * 128;   // m outer: 8 n-blocks share the A-tile
  const int n0 = (rem & 7) * 128;

  const int tid = threadIdx.x;
  const int w = tid >> 6, l = tid & 63;
  const int g = l >> 4, ll = l & 15;
  const int wr = w >> 1, wc = w & 1;

  const u16* Ab;
  const u16* Bb;
  if (KIND == 0) {
    Ab = A + (size_t)m0 * 1024;
    Bb = Bt + (size_t)z * 1048576 + (size_t)n0 * 1024;
  } else {  // split-K: z = K-half index
    Ab = A + (size_t)m0 * 1024 + z * 512;
    Bb = Bt + (size_t)n0 * 1024 + z * 512;
  }

  // ring-4: slot s -> A tile at SH[s][0..4095], B tile at SH[s][4096..8191]
  __shared__ u16 SH[4][8192];  // 64 KB

  const f32x4 zero = {0.f, 0.f, 0.f, 0.f};
  f32x4 acc[4][4];
#pragma unroll
  for (int i = 0; i < 4; ++i)
#pragma unroll
    for (int j = 0; j < 4; ++j) acc[i][j] = zero;

  // stage tile t2: per wave 2 chunks of 1KB each for A and B.
  // linear LDS dest; source k-slot pre-swizzled: slg = sl ^ ((row>>1)&3)
  auto stage = [&](int t2) {
    const int slot = t2 & 3;
    const int k0 = t2 * 32;
#pragma unroll
    for (int c = 0; c < 2; ++c) {
      const int chunk = c * 4 + w;               // 8 chunks x 16 rows
      const int row = chunk * 16 + (l >> 2);
      const int sl = l & 3;
      const int kk = k0 + ((sl ^ ((row >> 1) & 3)) << 3);
      gload16(Ab + (size_t)row * 1024 + kk, &SH[slot][chunk * 512]);
      gload16(Bb + (size_t)row * 1024 + kk, &SH[slot][4096 + chunk * 512]);
    }
  };

  const int NT = (KIND == 1) ? 16 : 32;
  stage(0); stage(1); stage(2);

#pragma unroll
  for (int t = 0; t < NT; ++t) {
    // force own loads for tile t landed; allow newest (beyond-t) tiles in flight
    const int beyond = (NT - 1) - t;
    if (beyond >= 2)      asm volatile("s_waitcnt vmcnt(8)" ::: "memory");
    else if (beyond == 1) asm volatile("s_waitcnt vmcnt(4)" ::: "memory");
    else                  asm volatile("s_waitcnt vmcnt(0)" ::: "memory");
    __builtin_amdgcn_s_barrier();   // now tile t is fully in LDS (all waves)

    const int slot = t & 3;
    const u16* As = &SH[slot][0];
    const u16* Bs = &SH[slot][4096];
    s16x8 af[4], bfr[4];
#pragma unroll
    for (int mf = 0; mf < 4; ++mf) {
      const int row = wr * 64 + mf * 16 + ll;
      af[mf] = *(const s16x8*)&As[row * 32 + ((g ^ ((row >> 1) & 3)) << 3)];
    }
#pragma unroll
    for (int nf = 0; nf < 4; ++nf) {
      const int row = wc * 64 + nf * 16 + ll;
      bfr[nf] = *(const s16x8*)&Bs[row * 32 + ((g ^ ((row >> 1) & 3)) << 3)];
    }

    if (t + 3 < NT) stage(t + 3);   // overwrites slot (t-1)&3: reads done

    __builtin_amdgcn_s_setprio(1);
#pragma unroll
    for (int mf = 0; mf < 4; ++mf)
#pragma unroll
      for (int nf = 0; nf < 4; ++nf)
        acc[mf][nf] = __builtin_amdgcn_mfma_f32_16x16x32_bf16(af[mf], bfr[nf],
                                                              acc[mf][nf], 0, 0, 0);
    __builtin_amdgcn_s_setprio(0);
  }
  __syncthreads();  // epilogue may reuse LDS

  if (KIND == 0) {
    u16* C = (u16*)Cout + (size_t)z * 4194304;
    if (z < 4) {
      // LDS tile-transpose (XOR-swizzled) -> 16B coalesced stores.
      u16* T = &SH[0][0];  // viewed as [128][128]
#pragma unroll
      for (int mf = 0; mf < 4; ++mf)
#pragma unroll
        for (int nf = 0; nf < 4; ++nf) {
          const int c = wc * 64 + nf * 16 + ll;
#pragma unroll
          for (int rg = 0; rg < 4; ++rg) {
            const int r = wr * 64 + mf * 16 + g * 4 + rg;
            T[r * 128 + (c ^ ((r & 7) << 4))] = f2b(acc[mf][nf][rg]);
          }
        }
      __syncthreads();
#pragma unroll
      for (int i = 0; i < 8; ++i) {
        const int R = (tid >> 4) + i * 16;
        const int c0 = (tid & 15) * 8;
        const s16x8 v = *(const s16x8*)&T[R * 128 + (c0 ^ ((R & 7) << 4))];
        *(s16x8*)&C[(size_t)(m0 + R) * 1024 + n0 + c0] = v;
      }
    } else {
      // V: lane's 4 rg-values are 4 consecutive tokens at fixed d -> u16x4.
#pragma unroll
      for (int mf = 0; mf < 4; ++mf)
#pragma unroll
        for (int nf = 0; nf < 4; ++nf) {
          const int col = n0 + wc * 64 + nf * 16 + ll;
          const int hh = col >> 6, d = col & 63;
          const int mb = m0 + wr * 64 + mf * 16 + g * 4;
          const int bb = mb >> 10, n = mb & 1023;
          u16x4 pk;
#pragma unroll
          for (int rg = 0; rg < 4; ++rg) pk[rg] = f2b(acc[mf][nf][rg]);
          *(u16x4*)&C[((size_t)((bb * 16 + hh) * 64 + d)) * 1024 + n] = pk;
        }
    }
  } else {
    float* C = (float*)Cout + (size_t)z * 4194304;
#pragma unroll
    for (int mf = 0; mf < 4; ++mf)
#pragma unroll
      for (int nf = 0; nf < 4; ++nf) {
        const int col = n0 + wc * 64 + nf * 16 + ll;
#pragma unroll
        for (int rg = 0; rg < 4; ++rg) {
          const int m = m0 + wr * 64 + mf * 16 + g * 4 + rg;
          C[(size_t)m * 1024 + col] = acc[mf][nf][rg];
        }
      }
  }
}

// ---------------------------------------------------------------------------
// reduce: out = P0 + P1 (f32, 4194304 elems)
// ---------------------------------------------------------------------------
__global__ __launch_bounds__(256)
void reduce_kernel(const float* __restrict__ P, float* __restrict__ out) {
  const int i = (blockIdx.x * 256 + threadIdx.x) * 4;
  const float4 a = *(const float4*)(P + i);
  const float4 b = *(const float4*)(P + 4194304 + i);
  float4 o;
  o.x = a.x + b.x; o.y = a.y + b.y; o.z = a.z + b.z; o.w = a.w + b.w;
  *(float4*)(out + i) = o;
}

// ---------------------------------------------------------------------------
// Fused causal flash attention (+optional SiLU epilogue), paired q-tiles.
// Q token-major (roped here); K token-major PRE-ROPED; Vt [(b*16+h)*64+d][n].
// Block handles q-tiles (p, 15-p) for one bh -> uniform 17 K-tiles of work.
// ---------------------------------------------------------------------------
template <int SILU>
__global__ __launch_bounds__(256)
void attn_kernel(const u16* __restrict__ Q, const u16* __restrict__ K,
                 const u16* __restrict__ Vt, u16* __restrict__ O,
                 const float* __restrict__ ct, const float* __restrict__ st) {
  const int lin = blockIdx.x + (blockIdx.y << 3);   // [0,512)
  const int role = (lin & 7) * 64 + (lin >> 3);     // bijective XCD swizzle
  const int p = role & 7, bh = role >> 3;
  const int q_lo = p, q_hi = 15 - p;
  const int b = bh >> 4, h = bh & 15;
  const int tid = threadIdx.x, w = tid >> 6, l = tid & 63;
  const int g = l >> 4, ll = l & 15;

  const u16* Qb = Q + (size_t)(b * 1024) * 1024 + h * 64;
  const u16* Kb = K + (size_t)(b * 1024) * 1024 + h * 64;
  const u16* Vb = Vt + (size_t)((b * 16 + h) * 64) * 1024;
  u16* Ob = O + (size_t)(b * 1024) * 1024 + h * 64;

  __shared__ u16 Ksh[2][64 * 72];   // [kpos][d] pre-roped, pad 72, dbuf
  __shared__ u16 Psh[4][16 * 72];   // per-wave P round-trip

  // --- Q fragments for both tiles: rope + 1/8 scale, A-layout ---
  s16x8 qfL[2], qfH[2];
  auto loadQ = [&](int qt, s16x8* qf) {
    const int qrow = qt * 64 + w * 16 + ll;
#pragma unroll
    for (int kc = 0; kc < 2; ++kc) {
      const int d0 = kc * 32 + g * 8;
      const int j0 = d0 >> 1;
      const float4 c4 = *(const float4*)(ct + qrow * 32 + j0);
      const float4 s4v = *(const float4*)(st + qrow * 32 + j0);
      const s16x8 qin = *(const s16x8*)(Qb + (size_t)qrow * 1024 + d0);
      s16x8 qo;
#pragma unroll
      for (int pp = 0; pp < 4; ++pp) {
        const float c = ((const float*)&c4)[pp], s = ((const float*)&s4v)[pp];
        const float x0 = b2f((u16)qin[2 * pp]), x1 = b2f((u16)qin[2 * pp + 1]);
        qo[2 * pp]     = (short)f2b((x0 * c - x1 * s) * 0.125f);
        qo[2 * pp + 1] = (short)f2b((x1 * c + x0 * s) * 0.125f);
      }
      qf[kc] = qo;
    }
  };
  loadQ(q_lo, qfL);
  loadQ(q_hi, qfH);

  float mL[4], lsL[4], mH[4], lsH[4];
  f32x4 oL[4], oH[4];
  const f32x4 zero = {0.f, 0.f, 0.f, 0.f};
#pragma unroll
  for (int rg = 0; rg < 4; ++rg) {
    mL[rg] = -3.0e38f; lsL[rg] = 0.f; mH[rg] = -3.0e38f; lsH[rg] = 0.f;
  }
#pragma unroll
  for (int df = 0; df < 4; ++df) { oL[df] = zero; oH[df] = zero; }

  const int srow = tid >> 2;        // 0..63
  const int sc0 = (tid & 3) * 16;   // 0,16,32,48

  s16x8 kr0, kr1;
  auto kload = [&](int t) {
    const u16* kp = Kb + (size_t)(t * 64 + srow) * 1024 + sc0;
    kr0 = *(const s16x8*)kp;
    kr1 = *(const s16x8*)(kp + 8);
  };
  auto kstore = [&](int bf) {
    *(s16x8*)&Ksh[bf][srow * 72 + sc0] = kr0;
    *(s16x8*)&Ksh[bf][srow * 72 + sc0 + 8] = kr1;
  };

  kload(0);
  kstore(0);
  __syncthreads();
  int buf = 0;

  for (int t = 0; t <= q_hi; ++t) {
    const bool pre = (t < q_hi);
    if (pre) kload(t + 1);            // issue loads early (T14)

    // V fragments direct from global (L2-resident), shared by both q-tiles
    s16x8 vb[2][4];
#pragma unroll
    for (int kc = 0; kc < 2; ++kc)
#pragma unroll
      for (int df = 0; df < 4; ++df)
        vb[kc][df] = *(const s16x8*)(Vb + (size_t)(df * 16 + ll) * 1024 +
                                     t * 64 + kc * 32 + g * 8);

    auto process = [&](const s16x8* qf, float* mm, float* ls, f32x4* o,
                       bool diag) {
      f32x4 s4[4];
      __builtin_amdgcn_s_setprio(1);
#pragma unroll
      for (int nf = 0; nf < 4; ++nf) {
        const s16x8 kb0 = *(const s16x8*)&Ksh[buf][(nf * 16 + ll) * 72 + g * 8];
        const s16x8 kb1 = *(const s16x8*)&Ksh[buf][(nf * 16 + ll) * 72 + 32 + g * 8];
        f32x4 sv = zero;
        sv = __builtin_amdgcn_mfma_f32_16x16x32_bf16(qf[0], kb0, sv, 0, 0, 0);
        sv = __builtin_amdgcn_mfma_f32_16x16x32_bf16(qf[1], kb1, sv, 0, 0, 0);
        s4[nf] = sv;
      }
      __builtin_amdgcn_s_setprio(0);

      if (diag) {  // causal mask inside diagonal tile (t == qt)
#pragma unroll
        for (int nf = 0; nf < 4; ++nf)
#pragma unroll
          for (int rg = 0; rg < 4; ++rg)
            if (nf * 16 + ll > w * 16 + g * 4 + rg) s4[nf][rg] = -3.0e38f;
      }

#pragma unroll
      for (int rg = 0; rg < 4; ++rg) {
        float rmax = fmaxf(fmaxf(s4[0][rg], s4[1][rg]),
                           fmaxf(s4[2][rg], s4[3][rg]));
        rmax = fmaxf(rmax, __shfl_xor(rmax, 1, 64));
        rmax = fmaxf(rmax, __shfl_xor(rmax, 2, 64));
        rmax = fmaxf(rmax, __shfl_xor(rmax, 4, 64));
        rmax = fmaxf(rmax, __shfl_xor(rmax, 8, 64));
        const float mn = fmaxf(mm[rg], rmax);
        const float scl = __expf(mm[rg] - mn);
        mm[rg] = mn;
        float ps = 0.f;
#pragma unroll
        for (int nf = 0; nf < 4; ++nf) {
          const float pv = __expf(s4[nf][rg] - mn);
          s4[nf][rg] = pv;
          ps += pv;
        }
        ls[rg] = ls[rg] * scl + ps;   // lane-partial; reduced at the end
#pragma unroll
        for (int df = 0; df < 4; ++df) o[df][rg] *= scl;
      }

#pragma unroll
      for (int nf = 0; nf < 4; ++nf)
#pragma unroll
        for (int rg = 0; rg < 4; ++rg)
          Psh[w][(g * 4 + rg) * 72 + nf * 16 + ll] = f2b(s4[nf][rg]);

      __builtin_amdgcn_s_setprio(1);
#pragma unroll
      for (int kc = 0; kc < 2; ++kc) {
        const s16x8 pa = *(const s16x8*)&Psh[w][ll * 72 + kc * 32 + g * 8];
#pragma unroll
        for (int df = 0; df < 4; ++df)
          o[df] = __builtin_amdgcn_mfma_f32_16x16x32_bf16(pa, vb[kc][df],
                                                          o[df], 0, 0, 0);
      }
      __builtin_amdgcn_s_setprio(0);
    };

    process(qfH, mH, lsH, oH, t == q_hi);
    if (t <= q_lo) process(qfL, mL, lsL, oL, t == q_lo);

    if (pre) kstore(buf ^ 1);         // vmcnt wait here, hidden under compute
    __syncthreads();
    buf ^= 1;
  }

  // ---- epilogue: normalize, optional SiLU, store token-major bf16 ----
  auto finish = [&](float* ls, f32x4* o, int qt) {
#pragma unroll
    for (int rg = 0; rg < 4; ++rg) {
      float v = ls[rg];
      v += __shfl_xor(v, 1, 64);
      v += __shfl_xor(v, 2, 64);
      v += __shfl_xor(v, 4, 64);
      v += __shfl_xor(v, 8, 64);
      ls[rg] = 1.f / v;
    }
#pragma unroll
    for (int df = 0; df < 4; ++df)
#pragma unroll
      for (int rg = 0; rg < 4; ++rg) {
        float val = o[df][rg] * ls[rg];
        if (SILU) val = val / (1.f + __expf(-val));
        Ob[(size_t)(qt * 64 + w * 16 + g * 4 + rg) * 1024 + df * 16 + ll] =
            f2b(val);
      }
  };
  finish(lsH, oH, q_hi);
  finish(lsL, oL, q_lo);
}

// ---------------------------------------------------------------------------
extern "C" void kernel_launch(void* const* d_in, const int* in_sizes, int n_in,
                              void* d_out, int out_size, void* d_ws, size_t ws_size,
                              hipStream_t stream) {
  (void)in_sizes; (void)n_in; (void)out_size; (void)ws_size;
  const float* tokens = (const float*)d_in[0];
  const float* gamma  = (const float*)d_in[1];
  const float* Wq     = (const float*)d_in[2];
  const float* Wk     = (const float*)d_in[3];
  const float* Wv     = (const float*)d_in[4];
  const float* Wo     = (const float*)d_in[5];
  float* out = (float*)d_out;

  // workspace layout (bf16 elems unless noted); total ~96.3 MB
  u16* x    = (u16*)d_ws;                       // [4096][1024]
  u16* wt   = x + (size_t)4096 * 1024;          // 8 x [1024][1024] transposed bf16
  u16* qkv  = wt + (size_t)8 * 1048576;         // Q,K0..2,V0..2 each [4096][1024]
  u16* outA = qkv + (size_t)7 * 4194304;        // attn out ping
  u16* outB = outA + 4194304;                   // attn out pong
  float* ct = (float*)(outB + 4194304);         // cos [1024][32]
  float* st = ct + 32768;                       // sin [1024][32]
  // split-K partials: reuse dead K/V slots (qkv slots 1..4) after attention
  float* Pp = (float*)(qkv + 1 * 4194304);      // 2 x [4096][1024] f32

  rmsnorm_kernel<<<4096, 256, 0, stream>>>(tokens, gamma, x);
  rope_kernel<<<128, 256, 0, stream>>>(ct, st);
  transw_kernel<<<dim3(32, 32, 8), 256, 0, stream>>>(Wq, Wk, Wv, Wo, wt);
  gemm_kernel<0><<<1792, 256, 0, stream>>>(x, wt, qkv);

  const size_t M4 = 4194304;
  ropek_kernel<<<dim3(4096, 3), 256, 0, stream>>>(qkv + M4, ct, st);

  attn_kernel<1><<<dim3(8, 64), 256, 0, stream>>>(qkv, qkv + 1 * M4, qkv + 4 * M4,
                                                  outA, ct, st);
  attn_kernel<1><<<dim3(8, 64), 256, 0, stream>>>(outA, qkv + 2 * M4, qkv + 5 * M4,
                                                  outB, ct, st);
  attn_kernel<0><<<dim3(8, 64), 256, 0, stream>>>(outB, qkv + 3 * M4, qkv + 6 * M4,
                                                  outA, ct, st);

  gemm_kernel<1><<<512, 256, 0, stream>>>(outA, wt + (size_t)7 * 1048576,
                                          (void*)Pp);
  reduce_kernel<<<4096, 256, 0, stream>>>(Pp, out);
}